// Round 4
// baseline (807.760 us; speedup 1.0000x reference)
//
#include <hip/hip_runtime.h>
#include <math.h>

#define L_TOT 4194304   // 2^22 upsampled samples
#define NFR   16384     // frames / f0 length
#define OUTN  4194048   // output length

// ---------- workspace layout (floats) ----------
// [0, L_TOT)                : cumsum tree levels 1..22 (packed)
// [L_TOT, 2*L_TOT)          : pulse signal
// [2*L_TOT + 0,   +512)     : twiddle cos  (cos(2*pi*j/1024))
// [2*L_TOT + 512, +1024)    : twiddle sin
// [2*L_TOT + 1024,+2048)    : hann window (1024)
// [2*L_TOT + 2048,+2048+NFR): f0 = exp(log_f0)

__device__ __forceinline__ int lvl_off(int a) {
  return L_TOT - (L_TOT >> (a - 1));
}

// linear_interp(exp(log_f0), 256) at position j — matches reference rounding (no FMA)
__device__ __forceinline__ float f0_up_val(const float* f0arr, int j) {
  float pos = __fadd_rn(__fmul_rn(__fadd_rn((float)j, 0.5f), 1.0f / 256.0f), -0.5f);
  pos = fminf(fmaxf(pos, 0.0f), 16383.0f);
  int lo = (int)pos;
  int hi = min(lo + 1, NFR - 1);
  float frac = __fadd_rn(pos, -(float)lo);
  float a = __fmul_rn(f0arr[lo], __fadd_rn(1.0f, -frac));
  float b = __fmul_rn(f0arr[hi], frac);
  return __fadd_rn(a, b);
}

// prefix sum of first m elements of f0_up, replicating jax.lax.associative_scan's
// balanced-tree association bit-exactly in f32: left-to-right sum of MSB->LSB
// dyadic-aligned blocks, each block a balanced pairwise tree.
// (Verified by unrolling associative_scan: P(6)=((a0+a1)+(a2+a3))+(a4+a5), etc.)
__device__ float prefix_sum(const float* W, const float* f0arr, int m) {
  float acc = 0.0f;
  bool first = true;
  int pos = 0;
  for (int a = 22; a >= 1; --a) {
    if (m & (1 << a)) {
      float node = W[lvl_off(a) + (pos >> a)];
      acc = first ? node : __fadd_rn(acc, node);
      first = false;
      pos += (1 << a);
    }
  }
  if (m & 1) {
    float node = f0_up_val(f0arr, pos);
    acc = first ? node : __fadd_rn(acc, node);
  }
  return acc;
}

// ---------- init: twiddles, window, f0 ----------
__global__ __launch_bounds__(256) void init_tables(const float* __restrict__ logf0,
                                                   float* __restrict__ W) {
  int g = blockIdx.x * 256 + threadIdx.x;
  float* twc = W + 2 * L_TOT;
  float* tws = twc + 512;
  float* wh  = twc + 1024;
  float* f0arr = twc + 2048;
  if (g < 512) {
    double a = (double)g * 3.14159265358979323846 / 512.0; // 2*pi*g/1024
    twc[g] = (float)cos(a);
    tws[g] = (float)sin(a);
  }
  if (g < 1024) {
    double a = (double)g * 3.14159265358979323846 / 512.0;
    wh[g] = (float)(0.5 - 0.5 * cos(a));
  }
  if (g >= 2048 && g < 2048 + NFR) {
    f0arr[g - 2048] = (float)exp((double)logf0[g - 2048]); // correctly-rounded expf
  }
}

// ---------- cumsum tree, levels 1..11 (per 2048-element block) ----------
__global__ __launch_bounds__(256) void tree_kernel(float* W) {
  const float* f0arr = W + 2 * L_TOT + 2048;
  __shared__ float A[2048];
  __shared__ float B[1024];
  int tid = threadIdx.x;
  int base = blockIdx.x * 2048;
  for (int i = tid; i < 2048; i += 256) A[i] = f0_up_val(f0arr, base + i);
  __syncthreads();
  float* src = A;
  float* dst = B;
  int cnt = 1024;
  for (int a = 1; a <= 11; ++a) {
    int gbase = base >> a;
    for (int i = tid; i < cnt; i += 256) {
      float v = __fadd_rn(src[2 * i], src[2 * i + 1]);
      dst[i] = v;
      W[lvl_off(a) + gbase + i] = v;
    }
    __syncthreads();
    float* tmp = src; src = dst; dst = tmp;
    cnt >>= 1;
  }
}

// ---------- cumsum tree, levels 12..22 (single block over 2048 level-11 nodes) ----------
__global__ __launch_bounds__(256) void tree_top_kernel(float* W) {
  __shared__ float A[2048];
  __shared__ float B[1024];
  int tid = threadIdx.x;
  for (int i = tid; i < 2048; i += 256) A[i] = W[lvl_off(11) + i];
  __syncthreads();
  float* src = A;
  float* dst = B;
  int cnt = 1024;
  for (int a = 12; a <= 22; ++a) {
    for (int i = tid; i < cnt; i += 256) {
      float v = __fadd_rn(src[2 * i], src[2 * i + 1]);
      dst[i] = v;
      W[lvl_off(a) + i] = v;
    }
    __syncthreads();
    float* tmp = src; src = dst; dst = tmp;
    cnt >>= 1;
  }
}

// ---------- impulse train ----------
// Thread i needs prefix(i+1) and prefix(i+2); the latter is thread i+1's former.
// Share via LDS: each block computes 257 prefixes instead of 512.
__global__ __launch_bounds__(256) void pulse_kernel(float* W) {
  const float* f0arr = W + 2 * L_TOT + 2048;
  __shared__ float P[258];
  int tid = threadIdx.x;
  int base = blockIdx.x * 256;
  int i = base + tid;
  P[tid + 1] = prefix_sum(W, f0arr, i + 1);
  if (tid == 0) {
    int m2 = base + 257;
    P[257] = (m2 <= L_TOT) ? prefix_sum(W, f0arr, m2) : 0.0f;
  }
  __syncthreads();
  float P1 = P[tid + 1];
  float P2 = (i == L_TOT - 1) ? prefix_sum(W, f0arr, 1)  // roll(-1) wraps to saw[0]
                              : P[tid + 2];
  float t1 = __fdiv_rn(P1, 24000.0f);
  float saw1 = __fadd_rn(t1, -floorf(t1));   // mod(x,1): exact frac for x>=0
  float t2 = __fdiv_rn(P2, 24000.0f);
  float saw2 = __fadd_rn(t2, -floorf(t2));
  float c = __fdiv_rn(f0_up_val(f0arr, i), 24000.0f);
  W[L_TOT + i] = __fadd_rn(__fadd_rn(saw1, -saw2), c);
}

// ---------- in-LDS radix-2 complex FFT, N=1024, 256 threads ----------
// dir = -1 forward (e^{-i}), +1 inverse (e^{+i}), unscaled.
__device__ void fft1024(float* fr, float* fi, const float* twc, const float* tws, int dir) {
  int tid = threadIdx.x;
  __syncthreads();
  for (int i = tid; i < 1024; i += 256) {
    int j = __brev((unsigned)i) >> 22;
    if (j > i) {
      float tr = fr[i]; fr[i] = fr[j]; fr[j] = tr;
      float ti = fi[i]; fi[i] = fi[j]; fi[j] = ti;
    }
  }
  __syncthreads();
  for (int s = 0; s < 10; ++s) {
    int half = 1 << s;
    for (int b = tid; b < 512; b += 256) {
      int grp = b >> s;
      int pos = b & (half - 1);
      int i0 = (grp << (s + 1)) + pos;
      int i1 = i0 + half;
      int j = pos << (9 - s);
      float wr = twc[j];
      float wi = (dir > 0) ? tws[j] : -tws[j];
      float br = fr[i1], bi = fi[i1];
      float tr = br * wr - bi * wi;
      float ti = br * wi + bi * wr;
      float ar = fr[i0], ai = fi[i0];
      fr[i0] = ar + tr; fi[i0] = ai + ti;
      fr[i1] = ar - tr; fi[i1] = ai - ti;
    }
    __syncthreads();
  }
}

// ---------- per-frame fused kernel ----------
// frame f: min-phase from env_per column; pack(noise,pulse) FFT; combine; inverse; OLA.
__global__ __launch_bounds__(256) void column_kernel(
    const float* __restrict__ noise,
    const float* __restrict__ envn,
    const float* __restrict__ envp,
    const float* __restrict__ W,
    float* __restrict__ out) {
  __shared__ float fr[1024], fi[1024];
  __shared__ float hr[513], hi2[513];
  __shared__ float twc[512], tws[512], wh[1024];
  int tid = threadIdx.x;
  int bid = blockIdx.x;
  // XCD swizzle: round-robin bid->XCD means XCD x sees f = x*2048 + j for
  // consecutive j -> each XCD streams a contiguous f-range (env L2 locality).
  int f = (bid & 7) * 2048 + (bid >> 3);
  const float* pulse = W + L_TOT;
  const float* gtab = W + 2 * L_TOT;

  for (int i = tid; i < 512; i += 256) { twc[i] = gtab[i]; tws[i] = gtab[512 + i]; }
  for (int i = tid; i < 1024; i += 256) wh[i] = gtab[1024 + i];
  for (int k = tid; k < 513; k += 256) hr[k] = envp[k * NFR + f]; // log amp column
  __syncthreads();

  // ---- cepstrum: cep = irfft(log amp) (even real spectrum) ----
  for (int i = tid; i < 1024; i += 256) {
    int k = (i <= 512) ? i : 1024 - i;
    fr[i] = hr[k];
    fi[i] = 0.0f;
  }
  fft1024(fr, fi, twc, tws, +1);
  // fold (1,2,...,2,1,0,...,0) with 1/1024 irfft scale
  float v0 = fr[tid];
  float v1 = fr[tid + 256];
  float v2 = fr[tid + 512];
  __syncthreads();
  float c0 = v0 * (1.0f / 1024.0f); if (tid != 0) c0 = c0 + c0;
  float c1 = v1 * (1.0f / 1024.0f); c1 = c1 + c1;
  float c2 = (tid == 0) ? v2 * (1.0f / 1024.0f) : 0.0f;
  fr[tid] = c0;        fi[tid] = 0.0f;
  fr[tid + 256] = c1;  fi[tid + 256] = 0.0f;
  fr[tid + 512] = c2;  fi[tid + 512] = 0.0f;
  fr[tid + 768] = 0.0f; fi[tid + 768] = 0.0f;
  fft1024(fr, fi, twc, tws, -1);
  // H = exp(G) (complex)
  for (int k = tid; k < 513; k += 256) {
    float er = expf(fr[k]);
    float si, co;
    sincosf(fi[k], &si, &co);
    hr[k] = er * co;
    hi2[k] = er * si;
  }
  __syncthreads();

  // ---- pack z = noise + i*pulse (windowed, reflect-padded frame), one FFT ----
  for (int i = tid; i < 1024; i += 256) {
    int q = 256 * f - 256 + i;          // original-signal index
    if (q < 0) q = -q;
    else if (q >= L_TOT) q = 2 * L_TOT - 2 - q;
    float wv = wh[i];
    fr[i] = noise[q] * wv;
    fi[i] = pulse[q] * wv;
  }
  fft1024(fr, fi, twc, tws, -1);

  // ---- unpack Sn, Sp; combine Y = Sp*H + Sn*exp(env_noi) ----
  for (int k = tid; k < 513; k += 256) {
    int k2 = (1024 - k) & 1023;
    float zr = fr[k], zi = fi[k];
    float yr = fr[k2], yi = fi[k2];
    float Ar = 0.5f * (zr + yr), Ai = 0.5f * (zi - yi);  // noise spectrum
    float Br = 0.5f * (zi + yi), Bi = 0.5f * (yr - zr);  // pulse spectrum
    float An = expf(envn[k * NFR + f]);
    float Hr = hr[k], Hi = hi2[k];
    hr[k]  = Br * Hr - Bi * Hi + Ar * An;
    hi2[k] = Br * Hi + Bi * Hr + Ai * An;
  }
  __syncthreads();

  // ---- hermitian inverse FFT, window, overlap-add ----
  for (int i = tid; i < 1024; i += 256) {
    if (i <= 512) { fr[i] = hr[i]; fi[i] = hi2[i]; }
    else { fr[i] = hr[1024 - i]; fi[i] = -hi2[1024 - i]; }
  }
  fft1024(fr, fi, twc, tws, +1);
  for (int i = tid; i < 1024; i += 256) {
    float y = fr[i] * (1.0f / 1024.0f) * wh[i];
    int t = 256 * f + i - 512;            // trim n_fft/2 from each side
    if (t >= 0 && t < OUTN) atomicAdd(&out[t], y);
  }
}

// ---------- divide by window-square overlap sum ----------
__global__ __launch_bounds__(256) void finalize_kernel(float* __restrict__ out,
                                                       const float* __restrict__ W) {
  const float* wh = W + 2 * L_TOT + 1024;
  int t = blockIdx.x * 256 + threadIdx.x;
  if (t >= OUTN) return;
  int p = t + 512;
  int jmin = max(0, (p - 768) >> 8);
  int jmax = min(NFR - 1, p >> 8);
  float wsq = 0.0f;
  for (int j = jmin; j <= jmax; ++j) {
    float w = wh[p - 256 * j];
    wsq += w * w;
  }
  out[t] = out[t] / fmaxf(wsq, 1e-11f);
}

extern "C" void kernel_launch(void* const* d_in, const int* in_sizes, int n_in,
                              void* d_out, int out_size, void* d_ws, size_t ws_size,
                              hipStream_t stream) {
  const float* logf0 = (const float*)d_in[0];
  const float* envn  = (const float*)d_in[1];
  const float* envp  = (const float*)d_in[2];
  const float* noise = (const float*)d_in[3];
  float* out = (float*)d_out;
  float* W = (float*)d_ws;

  init_tables<<<dim3(72), dim3(256), 0, stream>>>(logf0, W);
  tree_kernel<<<dim3(2048), dim3(256), 0, stream>>>(W);
  tree_top_kernel<<<dim3(1), dim3(256), 0, stream>>>(W);
  pulse_kernel<<<dim3(L_TOT / 256), dim3(256), 0, stream>>>(W);
  hipMemsetAsync(d_out, 0, (size_t)out_size * sizeof(float), stream);
  column_kernel<<<dim3(NFR), dim3(256), 0, stream>>>(noise, envn, envp, W, out);
  finalize_kernel<<<dim3((OUTN + 255) / 256), dim3(256), 0, stream>>>(out, W);
}

// Round 5
// 486.615 us; speedup vs baseline: 1.6600x; 1.6600x over previous
//
#include <hip/hip_runtime.h>
#include <math.h>

#define L_TOT 4194304   // 2^22 upsampled samples
#define NFR   16384     // frames / f0 length
#define OUTN  4194048   // output length

// ---------- workspace layout (floats) ----------
// [0, L_TOT)                : cumsum tree levels 1..22 (packed)
// [L_TOT, 2*L_TOT)          : pulse signal
// [2*L_TOT + 0,   +512)     : twiddle cos  (cos(2*pi*j/1024))
// [2*L_TOT + 512, +1024)    : twiddle sin
// [2*L_TOT + 1024,+2048)    : hann window (1024)
// [2*L_TOT + 2048,+2048+NFR): f0 = exp(log_f0)

__device__ __forceinline__ int lvl_off(int a) {
  return L_TOT - (L_TOT >> (a - 1));
}

// linear_interp(exp(log_f0), 256) at position j — matches reference rounding (no FMA)
__device__ __forceinline__ float f0_up_val(const float* f0arr, int j) {
  float pos = __fadd_rn(__fmul_rn(__fadd_rn((float)j, 0.5f), 1.0f / 256.0f), -0.5f);
  pos = fminf(fmaxf(pos, 0.0f), 16383.0f);
  int lo = (int)pos;
  int hi = min(lo + 1, NFR - 1);
  float frac = __fadd_rn(pos, -(float)lo);
  float a = __fmul_rn(f0arr[lo], __fadd_rn(1.0f, -frac));
  float b = __fmul_rn(f0arr[hi], frac);
  return __fadd_rn(a, b);
}

// prefix sum of first m elements of f0_up, replicating jax.lax.associative_scan's
// balanced-tree association bit-exactly in f32 (validated: passed, absmax 1.2e-4).
__device__ float prefix_sum(const float* W, const float* f0arr, int m) {
  float acc = 0.0f;
  bool first = true;
  int pos = 0;
  for (int a = 22; a >= 1; --a) {
    if (m & (1 << a)) {
      float node = W[lvl_off(a) + (pos >> a)];
      acc = first ? node : __fadd_rn(acc, node);
      first = false;
      pos += (1 << a);
    }
  }
  if (m & 1) {
    float node = f0_up_val(f0arr, pos);
    acc = first ? node : __fadd_rn(acc, node);
  }
  return acc;
}

// ---------- init: twiddles, window, f0 ----------
__global__ __launch_bounds__(256) void init_tables(const float* __restrict__ logf0,
                                                   float* __restrict__ W) {
  int g = blockIdx.x * 256 + threadIdx.x;
  float* twc = W + 2 * L_TOT;
  float* tws = twc + 512;
  float* wh  = twc + 1024;
  float* f0arr = twc + 2048;
  if (g < 512) {
    double a = (double)g * 3.14159265358979323846 / 512.0; // 2*pi*g/1024
    twc[g] = (float)cos(a);
    tws[g] = (float)sin(a);
  }
  if (g < 1024) {
    double a = (double)g * 3.14159265358979323846 / 512.0;
    wh[g] = (float)(0.5 - 0.5 * cos(a));
  }
  if (g >= 2048 && g < 2048 + NFR) {
    f0arr[g - 2048] = (float)exp((double)logf0[g - 2048]); // correctly-rounded expf
  }
}

// ---------- cumsum tree, levels 1..11 (per 2048-element block) ----------
__global__ __launch_bounds__(256) void tree_kernel(float* W) {
  const float* f0arr = W + 2 * L_TOT + 2048;
  __shared__ float A[2048];
  __shared__ float B[1024];
  int tid = threadIdx.x;
  int base = blockIdx.x * 2048;
  for (int i = tid; i < 2048; i += 256) A[i] = f0_up_val(f0arr, base + i);
  __syncthreads();
  float* src = A;
  float* dst = B;
  int cnt = 1024;
  for (int a = 1; a <= 11; ++a) {
    int gbase = base >> a;
    for (int i = tid; i < cnt; i += 256) {
      float v = __fadd_rn(src[2 * i], src[2 * i + 1]);
      dst[i] = v;
      W[lvl_off(a) + gbase + i] = v;
    }
    __syncthreads();
    float* tmp = src; src = dst; dst = tmp;
    cnt >>= 1;
  }
}

// ---------- cumsum tree, levels 12..22 (single block over 2048 level-11 nodes) ----------
__global__ __launch_bounds__(256) void tree_top_kernel(float* W) {
  __shared__ float A[2048];
  __shared__ float B[1024];
  int tid = threadIdx.x;
  for (int i = tid; i < 2048; i += 256) A[i] = W[lvl_off(11) + i];
  __syncthreads();
  float* src = A;
  float* dst = B;
  int cnt = 1024;
  for (int a = 12; a <= 22; ++a) {
    for (int i = tid; i < cnt; i += 256) {
      float v = __fadd_rn(src[2 * i], src[2 * i + 1]);
      dst[i] = v;
      W[lvl_off(a) + i] = v;
    }
    __syncthreads();
    float* tmp = src; src = dst; dst = tmp;
    cnt >>= 1;
  }
}

// ---------- impulse train ----------
// Thread i needs prefix(i+1) and prefix(i+2); the latter is thread i+1's former.
__global__ __launch_bounds__(256) void pulse_kernel(float* W) {
  const float* f0arr = W + 2 * L_TOT + 2048;
  __shared__ float P[258];
  int tid = threadIdx.x;
  int base = blockIdx.x * 256;
  int i = base + tid;
  P[tid + 1] = prefix_sum(W, f0arr, i + 1);
  if (tid == 0) {
    int m2 = base + 257;
    P[257] = (m2 <= L_TOT) ? prefix_sum(W, f0arr, m2) : 0.0f;
  }
  __syncthreads();
  float P1 = P[tid + 1];
  float P2 = (i == L_TOT - 1) ? prefix_sum(W, f0arr, 1)  // roll(-1) wraps to saw[0]
                              : P[tid + 2];
  float t1 = __fdiv_rn(P1, 24000.0f);
  float saw1 = __fadd_rn(t1, -floorf(t1));   // mod(x,1): exact frac for x>=0
  float t2 = __fdiv_rn(P2, 24000.0f);
  float saw2 = __fadd_rn(t2, -floorf(t2));
  float c = __fdiv_rn(f0_up_val(f0arr, i), 24000.0f);
  W[L_TOT + i] = __fadd_rn(__fadd_rn(saw1, -saw2), c);
}

// ---------- Stockham autosort radix-2 FFT, N=1024, 256 threads ----------
// No bit-reversal (the 2.26e8 bank-conflict source in R4): natural order in/out,
// ping-pong xr/xi <-> yr/yi. All LDS accesses <=2-way (free on CDNA4, m136).
// dir = -1 forward (e^{-i}), +1 inverse (e^{+i}), unscaled. Result in xr/xi.
__device__ void fft1024(float* xr, float* xi, float* yr, float* yi,
                        const float* twc, const float* tws, int dir) {
  int tid = threadIdx.x;
  float* sr = xr; float* si = xi;
  float* dr = yr; float* di = yi;
  __syncthreads();
  for (int s = 0; s < 10; ++s) {
    int m = 1 << s;
    for (int b = tid; b < 512; b += 256) {
      int t  = b & ~(m - 1);   // twiddle index = j*m
      int d0 = b + t;          // k + 2*j*m
      float wr = twc[t];
      float wi = (dir > 0) ? tws[t] : -tws[t];
      float c0r = sr[b],       c0i = si[b];
      float c1r = sr[b + 512], c1i = si[b + 512];
      float sumr = c0r + c1r, sumi = c0i + c1i;
      float difr = c0r - c1r, difi = c0i - c1i;
      dr[d0]     = sumr;
      di[d0]     = sumi;
      dr[d0 + m] = difr * wr - difi * wi;
      di[d0 + m] = difr * wi + difi * wr;
    }
    __syncthreads();
    float* tr = sr; sr = dr; dr = tr;
    float* ti = si; si = di; di = ti;
  }
  // 10 swaps -> result back in xr/xi
}

// ---------- per-frame fused kernel ----------
// frame f: min-phase from env_per column; pack(noise,pulse) FFT; combine; inverse; OLA.
__global__ __launch_bounds__(256) void column_kernel(
    const float* __restrict__ noise,
    const float* __restrict__ envn,
    const float* __restrict__ envp,
    const float* __restrict__ W,
    float* __restrict__ out) {
  __shared__ float fr[1024], fi[1024];
  __shared__ float yr[1024], yi[1024];   // Stockham ping-pong scratch
  __shared__ float hr[513], hi2[513];
  __shared__ float twc[512], tws[512], wh[1024];
  int tid = threadIdx.x;
  int bid = blockIdx.x;
  // XCD swizzle: each XCD streams a contiguous f-range (env L2 locality).
  int f = (bid & 7) * 2048 + (bid >> 3);
  const float* pulse = W + L_TOT;
  const float* gtab = W + 2 * L_TOT;

  for (int i = tid; i < 512; i += 256) { twc[i] = gtab[i]; tws[i] = gtab[512 + i]; }
  for (int i = tid; i < 1024; i += 256) wh[i] = gtab[1024 + i];
  for (int k = tid; k < 513; k += 256) hr[k] = envp[k * NFR + f]; // log amp column
  __syncthreads();

  // ---- cepstrum: cep = irfft(log amp) (even real spectrum) ----
  for (int i = tid; i < 1024; i += 256) {
    int k = (i <= 512) ? i : 1024 - i;
    fr[i] = hr[k];
    fi[i] = 0.0f;
  }
  fft1024(fr, fi, yr, yi, twc, tws, +1);
  // fold (1,2,...,2,1,0,...,0) with 1/1024 irfft scale
  float v0 = fr[tid];
  float v1 = fr[tid + 256];
  float v2 = fr[tid + 512];
  __syncthreads();
  float c0 = v0 * (1.0f / 1024.0f); if (tid != 0) c0 = c0 + c0;
  float c1 = v1 * (1.0f / 1024.0f); c1 = c1 + c1;
  float c2 = (tid == 0) ? v2 * (1.0f / 1024.0f) : 0.0f;
  fr[tid] = c0;        fi[tid] = 0.0f;
  fr[tid + 256] = c1;  fi[tid + 256] = 0.0f;
  fr[tid + 512] = c2;  fi[tid + 512] = 0.0f;
  fr[tid + 768] = 0.0f; fi[tid + 768] = 0.0f;
  fft1024(fr, fi, yr, yi, twc, tws, -1);
  // H = exp(G) (complex)
  for (int k = tid; k < 513; k += 256) {
    float er = expf(fr[k]);
    float si, co;
    sincosf(fi[k], &si, &co);
    hr[k] = er * co;
    hi2[k] = er * si;
  }
  __syncthreads();

  // ---- pack z = noise + i*pulse (windowed, reflect-padded frame), one FFT ----
  for (int i = tid; i < 1024; i += 256) {
    int q = 256 * f - 256 + i;          // original-signal index
    if (q < 0) q = -q;
    else if (q >= L_TOT) q = 2 * L_TOT - 2 - q;
    float wv = wh[i];
    fr[i] = noise[q] * wv;
    fi[i] = pulse[q] * wv;
  }
  fft1024(fr, fi, yr, yi, twc, tws, -1);

  // ---- unpack Sn, Sp; combine Y = Sp*H + Sn*exp(env_noi) ----
  for (int k = tid; k < 513; k += 256) {
    int k2 = (1024 - k) & 1023;
    float zr = fr[k], zi = fi[k];
    float yr2 = fr[k2], yi2 = fi[k2];
    float Ar = 0.5f * (zr + yr2), Ai = 0.5f * (zi - yi2);  // noise spectrum
    float Br = 0.5f * (zi + yi2), Bi = 0.5f * (yr2 - zr);  // pulse spectrum
    float An = expf(envn[k * NFR + f]);
    float Hr = hr[k], Hi = hi2[k];
    hr[k]  = Br * Hr - Bi * Hi + Ar * An;
    hi2[k] = Br * Hi + Bi * Hr + Ai * An;
  }
  __syncthreads();

  // ---- hermitian inverse FFT, window, overlap-add ----
  for (int i = tid; i < 1024; i += 256) {
    if (i <= 512) { fr[i] = hr[i]; fi[i] = hi2[i]; }
    else { fr[i] = hr[1024 - i]; fi[i] = -hi2[1024 - i]; }
  }
  fft1024(fr, fi, yr, yi, twc, tws, +1);
  for (int i = tid; i < 1024; i += 256) {
    float y = fr[i] * (1.0f / 1024.0f) * wh[i];
    int t = 256 * f + i - 512;            // trim n_fft/2 from each side
    if (t >= 0 && t < OUTN) atomicAdd(&out[t], y);
  }
}

// ---------- divide by window-square overlap sum ----------
__global__ __launch_bounds__(256) void finalize_kernel(float* __restrict__ out,
                                                       const float* __restrict__ W) {
  const float* wh = W + 2 * L_TOT + 1024;
  int t = blockIdx.x * 256 + threadIdx.x;
  if (t >= OUTN) return;
  int p = t + 512;
  int jmin = max(0, (p - 768) >> 8);
  int jmax = min(NFR - 1, p >> 8);
  float wsq = 0.0f;
  for (int j = jmin; j <= jmax; ++j) {
    float w = wh[p - 256 * j];
    wsq += w * w;
  }
  out[t] = out[t] / fmaxf(wsq, 1e-11f);
}

extern "C" void kernel_launch(void* const* d_in, const int* in_sizes, int n_in,
                              void* d_out, int out_size, void* d_ws, size_t ws_size,
                              hipStream_t stream) {
  const float* logf0 = (const float*)d_in[0];
  const float* envn  = (const float*)d_in[1];
  const float* envp  = (const float*)d_in[2];
  const float* noise = (const float*)d_in[3];
  float* out = (float*)d_out;
  float* W = (float*)d_ws;

  init_tables<<<dim3(72), dim3(256), 0, stream>>>(logf0, W);
  tree_kernel<<<dim3(2048), dim3(256), 0, stream>>>(W);
  tree_top_kernel<<<dim3(1), dim3(256), 0, stream>>>(W);
  pulse_kernel<<<dim3(L_TOT / 256), dim3(256), 0, stream>>>(W);
  hipMemsetAsync(d_out, 0, (size_t)out_size * sizeof(float), stream);
  column_kernel<<<dim3(NFR), dim3(256), 0, stream>>>(noise, envn, envp, W, out);
  finalize_kernel<<<dim3((OUTN + 255) / 256), dim3(256), 0, stream>>>(out, W);
}

// Round 6
// 394.395 us; speedup vs baseline: 2.0481x; 1.2338x over previous
//
#include <hip/hip_runtime.h>
#include <math.h>

#define L_TOT 4194304   // 2^22 upsampled samples
#define NFR   16384     // frames / f0 length
#define OUTN  4194048   // output length

// ---------- workspace layout (floats) ----------
// [0, L_TOT)                : cumsum tree levels 1..22 (packed)
// [L_TOT, 2*L_TOT)          : pulse signal
// [2*L_TOT + 0,   +512)     : twiddle cos  (cos(2*pi*j/1024))
// [2*L_TOT + 512, +1024)    : twiddle sin
// [2*L_TOT + 1024,+2048)    : hann window (1024)
// [2*L_TOT + 2048,+2048+NFR): f0 = exp(log_f0)

__device__ __forceinline__ int lvl_off(int a) {
  return L_TOT - (L_TOT >> (a - 1));
}

// linear_interp(exp(log_f0), 256) at position j — matches reference rounding (no FMA)
__device__ __forceinline__ float f0_up_val(const float* f0arr, int j) {
  float pos = __fadd_rn(__fmul_rn(__fadd_rn((float)j, 0.5f), 1.0f / 256.0f), -0.5f);
  pos = fminf(fmaxf(pos, 0.0f), 16383.0f);
  int lo = (int)pos;
  int hi = min(lo + 1, NFR - 1);
  float frac = __fadd_rn(pos, -(float)lo);
  float a = __fmul_rn(f0arr[lo], __fadd_rn(1.0f, -frac));
  float b = __fmul_rn(f0arr[hi], frac);
  return __fadd_rn(a, b);
}

// prefix sum of first m elements of f0_up, replicating jax.lax.associative_scan's
// balanced-tree association bit-exactly in f32 (validated R4/R5: passed, absmax 1.2e-4).
__device__ float prefix_sum(const float* W, const float* f0arr, int m) {
  float acc = 0.0f;
  bool first = true;
  int pos = 0;
  for (int a = 22; a >= 1; --a) {
    if (m & (1 << a)) {
      float node = W[lvl_off(a) + (pos >> a)];
      acc = first ? node : __fadd_rn(acc, node);
      first = false;
      pos += (1 << a);
    }
  }
  if (m & 1) {
    float node = f0_up_val(f0arr, pos);
    acc = first ? node : __fadd_rn(acc, node);
  }
  return acc;
}

// ---------- init: twiddles, window, f0 ----------
__global__ __launch_bounds__(256) void init_tables(const float* __restrict__ logf0,
                                                   float* __restrict__ W) {
  int g = blockIdx.x * 256 + threadIdx.x;
  float* twc = W + 2 * L_TOT;
  float* tws = twc + 512;
  float* wh  = twc + 1024;
  float* f0arr = twc + 2048;
  if (g < 512) {
    double a = (double)g * 3.14159265358979323846 / 512.0; // 2*pi*g/1024
    twc[g] = (float)cos(a);
    tws[g] = (float)sin(a);
  }
  if (g < 1024) {
    double a = (double)g * 3.14159265358979323846 / 512.0;
    wh[g] = (float)(0.5 - 0.5 * cos(a));
  }
  if (g >= 2048 && g < 2048 + NFR) {
    f0arr[g - 2048] = (float)exp((double)logf0[g - 2048]); // correctly-rounded expf
  }
}

// ---------- cumsum tree, levels 1..11 (per 2048-element block) ----------
__global__ __launch_bounds__(256) void tree_kernel(float* W) {
  const float* f0arr = W + 2 * L_TOT + 2048;
  __shared__ float A[2048];
  __shared__ float B[1024];
  int tid = threadIdx.x;
  int base = blockIdx.x * 2048;
  for (int i = tid; i < 2048; i += 256) A[i] = f0_up_val(f0arr, base + i);
  __syncthreads();
  float* src = A;
  float* dst = B;
  int cnt = 1024;
  for (int a = 1; a <= 11; ++a) {
    int gbase = base >> a;
    for (int i = tid; i < cnt; i += 256) {
      float v = __fadd_rn(src[2 * i], src[2 * i + 1]);
      dst[i] = v;
      W[lvl_off(a) + gbase + i] = v;
    }
    __syncthreads();
    float* tmp = src; src = dst; dst = tmp;
    cnt >>= 1;
  }
}

// ---------- cumsum tree, levels 12..22 (single block over 2048 level-11 nodes) ----------
__global__ __launch_bounds__(256) void tree_top_kernel(float* W) {
  __shared__ float A[2048];
  __shared__ float B[1024];
  int tid = threadIdx.x;
  for (int i = tid; i < 2048; i += 256) A[i] = W[lvl_off(11) + i];
  __syncthreads();
  float* src = A;
  float* dst = B;
  int cnt = 1024;
  for (int a = 12; a <= 22; ++a) {
    for (int i = tid; i < cnt; i += 256) {
      float v = __fadd_rn(src[2 * i], src[2 * i + 1]);
      dst[i] = v;
      W[lvl_off(a) + i] = v;
    }
    __syncthreads();
    float* tmp = src; src = dst; dst = tmp;
    cnt >>= 1;
  }
}

// ---------- impulse train ----------
// For a 256-aligned block, bits >=8 of m = base+r (r<=255) equal base's bits:
// the MSB-side fold is block-uniform. Compute it once (broadcast loads), then
// per-thread fold only levels 7..1 + the bit-0 f0_up term. Identical fold order
// and nodes -> bit-exact vs full prefix_sum. Carry cases (r=256,257) do full fold.
__global__ __launch_bounds__(256) void pulse_kernel(float* W) {
  const float* f0arr = W + 2 * L_TOT + 2048;
  __shared__ float P[258];
  int tid = threadIdx.x;
  int base = blockIdx.x * 256;
  int i = base + tid;

  // block-uniform top fold (levels 22..8 of base)
  float accT = 0.0f;
  bool firstT = true;
  {
    int pos = 0;
    for (int a = 22; a >= 8; --a) {
      if (base & (1 << a)) {
        float node = W[lvl_off(a) + (pos >> a)];
        accT = firstT ? node : __fadd_rn(accT, node);
        firstT = false;
        pos += (1 << a);
      }
    }
  }

  int r = tid + 1;               // m = base + r, r in [1,256]
  if (r <= 255) {
    float acc = accT;
    bool first = firstT;
    int pos = base;
    for (int a = 7; a >= 1; --a) {
      if (r & (1 << a)) {
        float node = W[lvl_off(a) + (pos >> a)];
        acc = first ? node : __fadd_rn(acc, node);
        first = false;
        pos += (1 << a);
      }
    }
    if (r & 1) {
      float node = f0_up_val(f0arr, pos);
      acc = first ? node : __fadd_rn(acc, node);
    }
    P[tid + 1] = acc;
  } else {
    P[tid + 1] = prefix_sum(W, f0arr, base + r);   // r==256: carry into top bits
  }
  if (tid == 0) {
    int m2 = base + 257;
    P[257] = (m2 <= L_TOT) ? prefix_sum(W, f0arr, m2) : 0.0f;
  }
  __syncthreads();
  float P1 = P[tid + 1];
  float P2 = (i == L_TOT - 1) ? prefix_sum(W, f0arr, 1)  // roll(-1) wraps to saw[0]
                              : P[tid + 2];
  float t1 = __fdiv_rn(P1, 24000.0f);
  float saw1 = __fadd_rn(t1, -floorf(t1));   // mod(x,1): exact frac for x>=0
  float t2 = __fdiv_rn(P2, 24000.0f);
  float saw2 = __fadd_rn(t2, -floorf(t2));
  float c = __fdiv_rn(f0_up_val(f0arr, i), 24000.0f);
  W[L_TOT + i] = __fadd_rn(__fadd_rn(saw1, -saw2), c);
}

// ---------- Stockham autosort radix-4 FFT, N=1024, 256 threads ----------
// Composition of two verified radix-2 Stockham stages (R5 kernel). Natural order
// in/out, no bit-reversal. 5 stages, 1 butterfly/thread/stage. Result lands in
// the ping buffer (pr/pi) after 5 swaps. DIR=-1 forward, +1 inverse, unscaled.
// Per stage, butterfly b: j=b/m, k=b%m, t=j*m; inputs src[b+{0,256,512,768}];
// outputs dst[4jm+k+{0,m,2m,3m}] = [S0+S1, u*(D+sE), v*(S0-S1), uv*(D-sE)]
// where S0=x0+x2, S1=x1+x3, D=x0-x2, E=x1-x3, s=DIR*i, u=w^t, v=w^2t,
// w=e^{DIR*2*pi*i/1024}.  (Checked symbolically at N=4, both directions.)
template <int DIR>
__device__ void fft1024_r4(float* xr, float* xi, float* pr, float* pi2,
                           const float* twc, const float* tws) {
  int tid = threadIdx.x;
  float* sr = xr; float* si = xi;
  float* dr = pr; float* di = pi2;
  __syncthreads();
#pragma unroll
  for (int s = 0; s < 5; ++s) {
    int m = 1 << (2 * s);
    int b = tid;
    int t = b & ~(m - 1);
    float ur = twc[t];
    float ui = (DIR > 0) ? tws[t] : -tws[t];
    float vr = twc[2 * t];
    float vi = (DIR > 0) ? tws[2 * t] : -tws[2 * t];
    float w3r = ur * vr - ui * vi;      // w^{3t} = u*v
    float w3i = ur * vi + ui * vr;
    float x0r = sr[b],       x0i = si[b];
    float x1r = sr[b + 256], x1i = si[b + 256];
    float x2r = sr[b + 512], x2i = si[b + 512];
    float x3r = sr[b + 768], x3i = si[b + 768];
    float s0r = x0r + x2r, s0i = x0i + x2i;
    float s1r = x1r + x3r, s1i = x1i + x3i;
    float d0r = x0r - x2r, d0i = x0i - x2i;
    float e1r = x1r - x3r, e1i = x1i - x3i;
    // sE = DIR*i*(x1-x3)
    float ser = (DIR > 0) ? -e1i : e1i;
    float sei = (DIR > 0) ? e1r : -e1r;
    int d0idx = b + 3 * t;              // 4jm + k
    dr[d0idx] = s0r + s1r;
    di[d0idx] = s0i + s1i;
    float t1r = d0r + ser, t1i = d0i + sei;
    dr[d0idx + m] = t1r * ur - t1i * ui;
    di[d0idx + m] = t1r * ui + t1i * ur;
    float t2r = s0r - s1r, t2i = s0i - s1i;
    dr[d0idx + 2 * m] = t2r * vr - t2i * vi;
    di[d0idx + 2 * m] = t2r * vi + t2i * vr;
    float t3r = d0r - ser, t3i = d0i - sei;
    dr[d0idx + 3 * m] = t3r * w3r - t3i * w3i;
    di[d0idx + 3 * m] = t3r * w3i + t3i * w3r;
    __syncthreads();
    float* tr = sr; sr = dr; dr = tr;
    float* ti = si; si = di; di = ti;
  }
  // 5 swaps: result in pr/pi2
}

// ---------- per-frame fused kernel ----------
// frame f: min-phase from env_per column; pack(noise,pulse) FFT; combine; inverse; OLA.
// Convention: FFT input in fr/fi, result in yr/yi.
__global__ __launch_bounds__(256) void column_kernel(
    const float* __restrict__ noise,
    const float* __restrict__ envn,
    const float* __restrict__ envp,
    const float* __restrict__ W,
    float* __restrict__ out) {
  __shared__ float fr[1024], fi[1024];
  __shared__ float yr[1024], yi[1024];   // ping buffer: FFT results land here
  __shared__ float hr[513], hi2[513];
  __shared__ float twc[512], tws[512], wh[1024];
  int tid = threadIdx.x;
  int bid = blockIdx.x;
  // XCD swizzle: each XCD streams a contiguous f-range (env L2 locality).
  int f = (bid & 7) * 2048 + (bid >> 3);
  const float* pulse = W + L_TOT;
  const float* gtab = W + 2 * L_TOT;

  for (int i = tid; i < 512; i += 256) { twc[i] = gtab[i]; tws[i] = gtab[512 + i]; }
  for (int i = tid; i < 1024; i += 256) wh[i] = gtab[1024 + i];
  for (int k = tid; k < 513; k += 256) hr[k] = envp[k * NFR + f]; // log amp column
  __syncthreads();

  // ---- cepstrum: cep = irfft(log amp) (even real spectrum) ----
  for (int i = tid; i < 1024; i += 256) {
    int k = (i <= 512) ? i : 1024 - i;
    fr[i] = hr[k];
    fi[i] = 0.0f;
  }
  fft1024_r4<+1>(fr, fi, yr, yi, twc, tws);
  // fold (1,2,...,2,1,0,...,0) with 1/1024 irfft scale; result -> fr/fi
  float v0 = yr[tid];
  float v1 = yr[tid + 256];
  float v2 = yr[tid + 512];
  float c0 = v0 * (1.0f / 1024.0f); if (tid != 0) c0 = c0 + c0;
  float c1 = v1 * (1.0f / 1024.0f); c1 = c1 + c1;
  float c2 = (tid == 0) ? v2 * (1.0f / 1024.0f) : 0.0f;
  fr[tid] = c0;        fi[tid] = 0.0f;
  fr[tid + 256] = c1;  fi[tid + 256] = 0.0f;
  fr[tid + 512] = c2;  fi[tid + 512] = 0.0f;
  fr[tid + 768] = 0.0f; fi[tid + 768] = 0.0f;
  fft1024_r4<-1>(fr, fi, yr, yi, twc, tws);
  // H = exp(G) (complex), G in yr/yi
  for (int k = tid; k < 513; k += 256) {
    float er = expf(yr[k]);
    float si, co;
    sincosf(yi[k], &si, &co);
    hr[k] = er * co;
    hi2[k] = er * si;
  }

  // ---- pack z = noise + i*pulse (windowed, reflect-padded frame), one FFT ----
  for (int i = tid; i < 1024; i += 256) {
    int q = 256 * f - 256 + i;          // original-signal index
    if (q < 0) q = -q;
    else if (q >= L_TOT) q = 2 * L_TOT - 2 - q;
    float wv = wh[i];
    fr[i] = noise[q] * wv;
    fi[i] = pulse[q] * wv;
  }
  fft1024_r4<-1>(fr, fi, yr, yi, twc, tws);

  // ---- unpack Sn, Sp from yr/yi; combine Y = Sp*H + Sn*exp(env_noi) ----
  for (int k = tid; k < 513; k += 256) {
    int k2 = (1024 - k) & 1023;
    float zr = yr[k], zi = yi[k];
    float mr = yr[k2], mi = yi[k2];
    float Ar = 0.5f * (zr + mr), Ai = 0.5f * (zi - mi);  // noise spectrum
    float Br = 0.5f * (zi + mi), Bi = 0.5f * (mr - zr);  // pulse spectrum
    float An = expf(envn[k * NFR + f]);
    float Hr = hr[k], Hi = hi2[k];
    hr[k]  = Br * Hr - Bi * Hi + Ar * An;
    hi2[k] = Br * Hi + Bi * Hr + Ai * An;
  }
  __syncthreads();

  // ---- hermitian inverse FFT, window, overlap-add ----
  for (int i = tid; i < 1024; i += 256) {
    if (i <= 512) { fr[i] = hr[i]; fi[i] = hi2[i]; }
    else { fr[i] = hr[1024 - i]; fi[i] = -hi2[1024 - i]; }
  }
  fft1024_r4<+1>(fr, fi, yr, yi, twc, tws);
  for (int i = tid; i < 1024; i += 256) {
    float y = yr[i] * (1.0f / 1024.0f) * wh[i];
    int t = 256 * f + i - 512;            // trim n_fft/2 from each side
    if (t >= 0 && t < OUTN) atomicAdd(&out[t], y);
  }
}

// ---------- divide by window-square overlap sum ----------
__global__ __launch_bounds__(256) void finalize_kernel(float* __restrict__ out,
                                                       const float* __restrict__ W) {
  const float* wh = W + 2 * L_TOT + 1024;
  int t = blockIdx.x * 256 + threadIdx.x;
  if (t >= OUTN) return;
  int p = t + 512;
  int jmin = max(0, (p - 768) >> 8);
  int jmax = min(NFR - 1, p >> 8);
  float wsq = 0.0f;
  for (int j = jmin; j <= jmax; ++j) {
    float w = wh[p - 256 * j];
    wsq += w * w;
  }
  out[t] = out[t] / fmaxf(wsq, 1e-11f);
}

extern "C" void kernel_launch(void* const* d_in, const int* in_sizes, int n_in,
                              void* d_out, int out_size, void* d_ws, size_t ws_size,
                              hipStream_t stream) {
  const float* logf0 = (const float*)d_in[0];
  const float* envn  = (const float*)d_in[1];
  const float* envp  = (const float*)d_in[2];
  const float* noise = (const float*)d_in[3];
  float* out = (float*)d_out;
  float* W = (float*)d_ws;

  init_tables<<<dim3(72), dim3(256), 0, stream>>>(logf0, W);
  tree_kernel<<<dim3(2048), dim3(256), 0, stream>>>(W);
  tree_top_kernel<<<dim3(1), dim3(256), 0, stream>>>(W);
  pulse_kernel<<<dim3(L_TOT / 256), dim3(256), 0, stream>>>(W);
  hipMemsetAsync(d_out, 0, (size_t)out_size * sizeof(float), stream);
  column_kernel<<<dim3(NFR), dim3(256), 0, stream>>>(noise, envn, envp, W, out);
  finalize_kernel<<<dim3((OUTN + 255) / 256), dim3(256), 0, stream>>>(out, W);
}

// Round 7
// 295.018 us; speedup vs baseline: 2.7380x; 1.3368x over previous
//
#include <hip/hip_runtime.h>
#include <math.h>

#define L_TOT 4194304   // 2^22 upsampled samples
#define NFR   16384     // frames / f0 length
#define OUTN  4194048   // output length

// ---------- workspace layout (floats) ----------
// [0, L_TOT)                : cumsum tree levels 1..22 (packed; levels 1..7 unused/not stored)
// [L_TOT, 2*L_TOT)          : pulse signal
// [2*L_TOT + 0,   +512)     : twiddle cos  (cos(2*pi*j/1024))
// [2*L_TOT + 512, +1024)    : twiddle sin
// [2*L_TOT + 1024,+2048)    : hann window (1024) — used by finalize
// [2*L_TOT + 2048,+2048+NFR): f0 = exp(log_f0)

__device__ __forceinline__ int lvl_off(int a) {
  return L_TOT - (L_TOT >> (a - 1));
}

// linear_interp(exp(log_f0), 256) at position j — matches reference rounding (no FMA)
__device__ __forceinline__ float f0_up_val(const float* f0arr, int j) {
  float pos = __fadd_rn(__fmul_rn(__fadd_rn((float)j, 0.5f), 1.0f / 256.0f), -0.5f);
  pos = fminf(fmaxf(pos, 0.0f), 16383.0f);
  int lo = (int)pos;
  int hi = min(lo + 1, NFR - 1);
  float frac = __fadd_rn(pos, -(float)lo);
  float a = __fmul_rn(f0arr[lo], __fadd_rn(1.0f, -frac));
  float b = __fmul_rn(f0arr[hi], frac);
  return __fadd_rn(a, b);
}

// full prefix sum (levels 22..1), replicating jax.lax.associative_scan bit-exactly.
// Only called with m ≡ 0 or 1 (mod 256) -> never reads levels 1..7 (not stored).
__device__ float prefix_sum(const float* W, const float* f0arr, int m) {
  float acc = 0.0f;
  bool first = true;
  int pos = 0;
  for (int a = 22; a >= 1; --a) {
    if (m & (1 << a)) {
      float node = W[lvl_off(a) + (pos >> a)];
      acc = first ? node : __fadd_rn(acc, node);
      first = false;
      pos += (1 << a);
    }
  }
  if (m & 1) {
    float node = f0_up_val(f0arr, pos);
    acc = first ? node : __fadd_rn(acc, node);
  }
  return acc;
}

// ---------- init: twiddles, window, f0 ----------
__global__ __launch_bounds__(256) void init_tables(const float* __restrict__ logf0,
                                                   float* __restrict__ W) {
  int g = blockIdx.x * 256 + threadIdx.x;
  float* twc = W + 2 * L_TOT;
  float* tws = twc + 512;
  float* wh  = twc + 1024;
  float* f0arr = twc + 2048;
  if (g < 512) {
    double a = (double)g * 3.14159265358979323846 / 512.0; // 2*pi*g/1024
    twc[g] = (float)cos(a);
    tws[g] = (float)sin(a);
  }
  if (g < 1024) {
    double a = (double)g * 3.14159265358979323846 / 512.0;
    wh[g] = (float)(0.5 - 0.5 * cos(a));
  }
  if (g >= 2048 && g < 2048 + NFR) {
    f0arr[g - 2048] = (float)exp((double)logf0[g - 2048]); // correctly-rounded expf
  }
}

// ---------- cumsum tree, levels 1..11; store only >=8 (pulse builds 1..7 in LDS) ----------
__global__ __launch_bounds__(256) void tree_kernel(float* W) {
  const float* f0arr = W + 2 * L_TOT + 2048;
  __shared__ float A[2048];
  __shared__ float B[1024];
  int tid = threadIdx.x;
  int base = blockIdx.x * 2048;
  for (int i = tid; i < 2048; i += 256) A[i] = f0_up_val(f0arr, base + i);
  __syncthreads();
  float* src = A;
  float* dst = B;
  int cnt = 1024;
  for (int a = 1; a <= 11; ++a) {
    int gbase = base >> a;
    for (int i = tid; i < cnt; i += 256) {
      float v = __fadd_rn(src[2 * i], src[2 * i + 1]);
      dst[i] = v;
      if (a >= 8) W[lvl_off(a) + gbase + i] = v;
    }
    __syncthreads();
    float* tmp = src; src = dst; dst = tmp;
    cnt >>= 1;
  }
}

// ---------- cumsum tree, levels 12..22 ----------
__global__ __launch_bounds__(256) void tree_top_kernel(float* W) {
  __shared__ float A[2048];
  __shared__ float B[1024];
  int tid = threadIdx.x;
  for (int i = tid; i < 2048; i += 256) A[i] = W[lvl_off(11) + i];
  __syncthreads();
  float* src = A;
  float* dst = B;
  int cnt = 1024;
  for (int a = 12; a <= 22; ++a) {
    for (int i = tid; i < cnt; i += 256) {
      float v = __fadd_rn(src[2 * i], src[2 * i + 1]);
      dst[i] = v;
      W[lvl_off(a) + i] = v;
    }
    __syncthreads();
    float* tmp = src; src = dst; dst = tmp;
    cnt >>= 1;
  }
}

// ---------- impulse train ----------
// Levels 1..7 rebuilt in LDS from the block's f0_up values (bit-exact: same
// pairwise __fadd_rn on same inputs) -> zero scattered global loads in the
// per-thread fold. Top fold (levels 22..8 of base) is block-uniform broadcast.
__global__ __launch_bounds__(256) void pulse_kernel(float* W) {
  const float* f0arr = W + 2 * L_TOT + 2048;
  __shared__ float f0v[256];
  __shared__ float Tl[254];   // level a at offset 256-(256>>(a-1)), size 256>>a
  __shared__ float P[258];
  int tid = threadIdx.x;
  int base = blockIdx.x * 256;
  int i = base + tid;

  f0v[tid] = f0_up_val(f0arr, i);
  __syncthreads();
  if (tid < 128) Tl[tid]       = __fadd_rn(f0v[2 * tid], f0v[2 * tid + 1]);
  __syncthreads();
  if (tid < 64)  Tl[128 + tid] = __fadd_rn(Tl[2 * tid], Tl[2 * tid + 1]);
  __syncthreads();
  if (tid < 32)  Tl[192 + tid] = __fadd_rn(Tl[128 + 2 * tid], Tl[128 + 2 * tid + 1]);
  __syncthreads();
  if (tid < 16)  Tl[224 + tid] = __fadd_rn(Tl[192 + 2 * tid], Tl[192 + 2 * tid + 1]);
  __syncthreads();
  if (tid < 8)   Tl[240 + tid] = __fadd_rn(Tl[224 + 2 * tid], Tl[224 + 2 * tid + 1]);
  __syncthreads();
  if (tid < 4)   Tl[248 + tid] = __fadd_rn(Tl[240 + 2 * tid], Tl[240 + 2 * tid + 1]);
  __syncthreads();
  if (tid < 2)   Tl[252 + tid] = __fadd_rn(Tl[248 + 2 * tid], Tl[248 + 2 * tid + 1]);
  __syncthreads();

  // block-uniform top fold (levels 22..8 of base)
  float accT = 0.0f;
  bool firstT = true;
  {
    int pos = 0;
    for (int a = 22; a >= 8; --a) {
      if (base & (1 << a)) {
        float node = W[lvl_off(a) + (pos >> a)];
        accT = firstT ? node : __fadd_rn(accT, node);
        firstT = false;
        pos += (1 << a);
      }
    }
  }

  int r = tid + 1;               // m = base + r, r in [1,256]
  if (r <= 255) {
    float acc = accT;
    bool first = firstT;
    int lpos = 0;
    for (int a = 7; a >= 1; --a) {
      if (r & (1 << a)) {
        float node = Tl[256 - (256 >> (a - 1)) + (lpos >> a)];
        acc = first ? node : __fadd_rn(acc, node);
        first = false;
        lpos += (1 << a);
      }
    }
    if (r & 1) {
      float node = f0v[lpos];
      acc = first ? node : __fadd_rn(acc, node);
    }
    P[r] = acc;
  } else {
    P[256] = prefix_sum(W, f0arr, base + 256);   // r==256: carry into top bits
  }
  if (tid == 0) {
    int m2 = base + 257;
    P[257] = (m2 <= L_TOT) ? prefix_sum(W, f0arr, m2) : 0.0f;
  }
  __syncthreads();
  float P1 = P[tid + 1];
  float P2 = (i == L_TOT - 1) ? prefix_sum(W, f0arr, 1)  // roll(-1) wraps to saw[0]
                              : P[tid + 2];
  float t1 = __fdiv_rn(P1, 24000.0f);
  float saw1 = __fadd_rn(t1, -floorf(t1));   // mod(x,1): exact frac for x>=0
  float t2 = __fdiv_rn(P2, 24000.0f);
  float saw2 = __fadd_rn(t2, -floorf(t2));
  float c = __fdiv_rn(f0v[tid], 24000.0f);
  W[L_TOT + i] = __fadd_rn(__fadd_rn(saw1, -saw2), c);
}

// ---------- Stockham autosort radix-4 FFT, N=1024, 256 threads (validated R6) ----------
// Natural order in/out; result lands in pr/pi2 after 5 stages.
template <int DIR>
__device__ void fft1024_r4(float* xr, float* xi, float* pr, float* pi2,
                           const float* twc, const float* tws) {
  int tid = threadIdx.x;
  float* sr = xr; float* si = xi;
  float* dr = pr; float* di = pi2;
  __syncthreads();
#pragma unroll
  for (int s = 0; s < 5; ++s) {
    int m = 1 << (2 * s);
    int b = tid;
    int t = b & ~(m - 1);
    float ur = twc[t];
    float ui = (DIR > 0) ? tws[t] : -tws[t];
    float vr = twc[2 * t];
    float vi = (DIR > 0) ? tws[2 * t] : -tws[2 * t];
    float w3r = ur * vr - ui * vi;      // w^{3t} = u*v
    float w3i = ur * vi + ui * vr;
    float x0r = sr[b],       x0i = si[b];
    float x1r = sr[b + 256], x1i = si[b + 256];
    float x2r = sr[b + 512], x2i = si[b + 512];
    float x3r = sr[b + 768], x3i = si[b + 768];
    float s0r = x0r + x2r, s0i = x0i + x2i;
    float s1r = x1r + x3r, s1i = x1i + x3i;
    float d0r = x0r - x2r, d0i = x0i - x2i;
    float e1r = x1r - x3r, e1i = x1i - x3i;
    float ser = (DIR > 0) ? -e1i : e1i;
    float sei = (DIR > 0) ? e1r : -e1r;
    int d0idx = b + 3 * t;              // 4jm + k
    dr[d0idx] = s0r + s1r;
    di[d0idx] = s0i + s1i;
    float t1r = d0r + ser, t1i = d0i + sei;
    dr[d0idx + m] = t1r * ur - t1i * ui;
    di[d0idx + m] = t1r * ui + t1i * ur;
    float t2r = s0r - s1r, t2i = s0i - s1i;
    dr[d0idx + 2 * m] = t2r * vr - t2i * vi;
    di[d0idx + 2 * m] = t2r * vi + t2i * vr;
    float t3r = d0r - ser, t3i = d0i - sei;
    dr[d0idx + 3 * m] = t3r * w3r - t3i * w3i;
    di[d0idx + 3 * m] = t3r * w3i + t3i * w3r;
    __syncthreads();
    float* tr = sr; sr = dr; dr = tr;
    float* ti = si; si = di; di = ti;
  }
}

// Hann window from the twiddle table: w(i) = 0.5 - 0.5*cos(2*pi*i/1024)
__device__ __forceinline__ float hann_w(int i, const float* twc) {
  float c = (i == 512) ? -1.0f : ((i < 512) ? twc[i] : twc[1024 - i]);
  return 0.5f - 0.5f * c;
}

// spectral combine for one bin: Y[k] = Sp[k]*H[k] + Sn[k]*An, H from hr/hi (overwritten)
__device__ __forceinline__ void combine_one(int k, float An, const float* yr,
                                            const float* yi, float* hr, float* hi) {
  int k2 = (1024 - k) & 1023;
  float zr = yr[k], zi = yi[k];
  float mr = yr[k2], mi = yi[k2];
  float Ar = 0.5f * (zr + mr), Ai = 0.5f * (zi - mi);  // even (noise) part
  float Br = 0.5f * (zi + mi), Bi = 0.5f * (mr - zr);  // odd (pulse) part
  float Hr = hr[k], Hi = hi[k];
  hr[k] = Br * Hr - Bi * Hi + Ar * An;
  hi[k] = Br * Hi + Bi * Hr + Ai * An;
}

// ---------- per-block fused kernel: TWO adjacent frames, 5 FFTs ----------
// (1) cep pair: both inputs real-even -> one FFT, Re/Im split.
// (2) rfft pair: two real cepstra -> one FFT, hermitian unpack -> HA, HB.
// (3,4) per-frame pack z=noise+i*pulse (as R4-R6, validated).
// (5) inverse pair: Z = YA_full + i*YB_full -> one FFT -> yA + i*yB.
__global__ __launch_bounds__(256) void column_kernel(
    const float* __restrict__ noise,
    const float* __restrict__ envn,
    const float* __restrict__ envp,
    const float* __restrict__ W,
    float* __restrict__ out) {
  __shared__ float fr[1024], fi[1024];
  __shared__ float yr[1024], yi[1024];   // ping buffer: FFT results land here
  __shared__ float hAr[513], hAi[513], hBr[513], hBi[513];
  __shared__ float twc[512], tws[512];
  int tid = threadIdx.x;
  int bid = blockIdx.x;
  // XCD swizzle: each XCD streams a contiguous frame range (env L2 locality).
  int g = (bid & 7) * 1024 + (bid >> 3);
  int fA = 2 * g;                        // frames fA, fA+1
  const float* pulse = W + L_TOT;
  const float* gtab = W + 2 * L_TOT;

  for (int i = tid; i < 512; i += 256) { twc[i] = gtab[i]; tws[i] = gtab[512 + i]; }
  for (int k = tid; k < 513; k += 256) {
    float2 e = *(const float2*)&envp[k * NFR + fA];   // fA even -> 8B aligned
    hAr[k] = e.x;                                     // log amp col, frame A
    hBr[k] = e.y;                                     // frame B
  }
  __syncthreads();

  // ---- (1) packed cepstrum: z = envA_sym + i*envB_sym (both real even) ----
  for (int i = tid; i < 1024; i += 256) {
    int k = (i <= 512) ? i : 1024 - i;
    fr[i] = hAr[k];
    fi[i] = hBr[k];
  }
  fft1024_r4<+1>(fr, fi, yr, yi, twc, tws);
  // cepA = yr*fold/1024, cepB = yi*fold/1024 (spectra of real-even are real)
  {
    float a0 = yr[tid], b0 = yi[tid];
    float a1 = yr[tid + 256], b1 = yi[tid + 256];
    float a2 = yr[tid + 512], b2 = yi[tid + 512];
    float s0 = (tid == 0) ? (1.0f / 1024.0f) : (2.0f / 1024.0f);  // exact p2 scales
    fr[tid] = a0 * s0;          fi[tid] = b0 * s0;
    fr[tid + 256] = a1 * (2.0f / 1024.0f);
    fi[tid + 256] = b1 * (2.0f / 1024.0f);
    fr[tid + 512] = (tid == 0) ? a2 * (1.0f / 1024.0f) : 0.0f;
    fi[tid + 512] = (tid == 0) ? b2 * (1.0f / 1024.0f) : 0.0f;
    fr[tid + 768] = 0.0f;       fi[tid + 768] = 0.0f;
  }
  // ---- (2) packed rfft of two real cepstra; unpack hermitian; H=exp ----
  fft1024_r4<-1>(fr, fi, yr, yi, twc, tws);
  for (int k = tid; k < 513; k += 256) {
    int k2 = (1024 - k) & 1023;
    float zr = yr[k], zi = yi[k];
    float mr = yr[k2], mi = yi[k2];
    float GAr = 0.5f * (zr + mr), GAi = 0.5f * (zi - mi);
    float GBr = 0.5f * (zi + mi), GBi = 0.5f * (mr - zr);
    float er = expf(GAr);
    float si, co;
    sincosf(GAi, &si, &co);
    hAr[k] = er * co; hAi[k] = er * si;
    er = expf(GBr);
    sincosf(GBi, &si, &co);
    hBr[k] = er * co; hBi[k] = er * si;
  }

  // ---- (3) frame A: pack z = noise + i*pulse (windowed, reflect-padded) ----
  for (int i = tid; i < 1024; i += 256) {
    int q = 256 * fA - 256 + i;
    if (q < 0) q = -q;
    else if (q >= L_TOT) q = 2 * L_TOT - 2 - q;
    float wv = hann_w(i, twc);
    fr[i] = noise[q] * wv;
    fi[i] = pulse[q] * wv;
  }
  fft1024_r4<-1>(fr, fi, yr, yi, twc, tws);
  // combine A; stash frame-B envn in registers (float2 load, fB = fA+1)
  float2 eA0 = *(const float2*)&envn[tid * NFR + fA];
  combine_one(tid, expf(eA0.x), yr, yi, hAr, hAi);
  float2 eA1 = *(const float2*)&envn[(tid + 256) * NFR + fA];
  combine_one(tid + 256, expf(eA1.x), yr, yi, hAr, hAi);
  float2 eA2 = make_float2(0.0f, 0.0f);
  if (tid == 0) {
    eA2 = *(const float2*)&envn[512 * NFR + fA];
    combine_one(512, expf(eA2.x), yr, yi, hAr, hAi);
  }

  // ---- (4) frame B ----
  for (int i = tid; i < 1024; i += 256) {
    int q = 256 * fA + i;                     // frame fA+1 start - 256
    if (q >= L_TOT) q = 2 * L_TOT - 2 - q;    // q >= 0 always here
    float wv = hann_w(i, twc);
    fr[i] = noise[q] * wv;
    fi[i] = pulse[q] * wv;
  }
  fft1024_r4<-1>(fr, fi, yr, yi, twc, tws);
  combine_one(tid, expf(eA0.y), yr, yi, hBr, hBi);
  combine_one(tid + 256, expf(eA1.y), yr, yi, hBr, hBi);
  if (tid == 0) combine_one(512, expf(eA2.y), yr, yi, hBr, hBi);
  __syncthreads();   // hB writes must be visible to cross-thread build below

  // ---- (5) packed hermitian inverse: Z = YA_full + i*YB_full ----
  for (int i = tid; i < 1024; i += 256) {
    if (i <= 512) {
      fr[i] = hAr[i] - hBi[i];
      fi[i] = hAi[i] + hBr[i];
    } else {
      int j = 1024 - i;
      fr[i] = hAr[j] + hBi[j];
      fi[i] = hBr[j] - hAi[j];
    }
  }
  fft1024_r4<+1>(fr, fi, yr, yi, twc, tws);
  for (int i = tid; i < 1024; i += 256) {
    float wv = hann_w(i, twc) * (1.0f / 1024.0f);
    float ya = yr[i] * wv;                 // frame A sample
    float yb = yi[i] * wv;                 // frame B sample
    int tA = 256 * fA + i - 512;
    if (tA >= 0 && tA < OUTN) atomicAdd(&out[tA], ya);
    int tB = tA + 256;
    if (tB >= 0 && tB < OUTN) atomicAdd(&out[tB], yb);
  }
}

// ---------- divide by window-square overlap sum ----------
__global__ __launch_bounds__(256) void finalize_kernel(float* __restrict__ out,
                                                       const float* __restrict__ W) {
  const float* wh = W + 2 * L_TOT + 1024;
  int t = blockIdx.x * 256 + threadIdx.x;
  if (t >= OUTN) return;
  int p = t + 512;
  int jmin = max(0, (p - 768) >> 8);
  int jmax = min(NFR - 1, p >> 8);
  float wsq = 0.0f;
  for (int j = jmin; j <= jmax; ++j) {
    float w = wh[p - 256 * j];
    wsq += w * w;
  }
  out[t] = out[t] / fmaxf(wsq, 1e-11f);
}

extern "C" void kernel_launch(void* const* d_in, const int* in_sizes, int n_in,
                              void* d_out, int out_size, void* d_ws, size_t ws_size,
                              hipStream_t stream) {
  const float* logf0 = (const float*)d_in[0];
  const float* envn  = (const float*)d_in[1];
  const float* envp  = (const float*)d_in[2];
  const float* noise = (const float*)d_in[3];
  float* out = (float*)d_out;
  float* W = (float*)d_ws;

  init_tables<<<dim3(72), dim3(256), 0, stream>>>(logf0, W);
  tree_kernel<<<dim3(2048), dim3(256), 0, stream>>>(W);
  tree_top_kernel<<<dim3(1), dim3(256), 0, stream>>>(W);
  pulse_kernel<<<dim3(L_TOT / 256), dim3(256), 0, stream>>>(W);
  hipMemsetAsync(d_out, 0, (size_t)out_size * sizeof(float), stream);
  column_kernel<<<dim3(NFR / 2), dim3(256), 0, stream>>>(noise, envn, envp, W, out);
  finalize_kernel<<<dim3((OUTN + 255) / 256), dim3(256), 0, stream>>>(out, W);
}

// Round 8
// 265.329 us; speedup vs baseline: 3.0444x; 1.1119x over previous
//
#include <hip/hip_runtime.h>
#include <math.h>

#define L_TOT 4194304   // 2^22 upsampled samples
#define NFR   16384     // frames / f0 length
#define OUTN  4194048   // output length

// ---------- workspace layout (floats) ----------
// [0, L_TOT)                : cumsum tree levels 10..22 (packed; levels 1..9 built in LDS)
// [L_TOT, 2*L_TOT)          : pulse signal
// [2*L_TOT + 0,   +512)     : twiddle cos  (cos(2*pi*j/1024))
// [2*L_TOT + 512, +1024)    : twiddle sin
// [2*L_TOT + 1024,+2048)    : hann window (1024) — used by edge finalize
// [2*L_TOT + 2048,+2048+NFR): f0 = exp(log_f0)

__device__ __forceinline__ int lvl_off(int a) {
  return L_TOT - (L_TOT >> (a - 1));
}

// linear_interp(exp(log_f0), 256) at position j — matches reference rounding (no FMA)
__device__ __forceinline__ float f0_up_val(const float* f0arr, int j) {
  float pos = __fadd_rn(__fmul_rn(__fadd_rn((float)j, 0.5f), 1.0f / 256.0f), -0.5f);
  pos = fminf(fmaxf(pos, 0.0f), 16383.0f);
  int lo = (int)pos;
  int hi = min(lo + 1, NFR - 1);
  float frac = __fadd_rn(pos, -(float)lo);
  float a = __fmul_rn(f0arr[lo], __fadd_rn(1.0f, -frac));
  float b = __fmul_rn(f0arr[hi], frac);
  return __fadd_rn(a, b);
}

// full prefix sum replicating jax.lax.associative_scan bit-exactly (validated R4-R7).
// Only called with m ≡ 0 or ±1 (mod 1024) -> never reads levels 1..9 (not stored).
__device__ float prefix_sum(const float* W, const float* f0arr, int m) {
  float acc = 0.0f;
  bool first = true;
  int pos = 0;
  for (int a = 22; a >= 1; --a) {
    if (m & (1 << a)) {
      float node = W[lvl_off(a) + (pos >> a)];
      acc = first ? node : __fadd_rn(acc, node);
      first = false;
      pos += (1 << a);
    }
  }
  if (m & 1) {
    float node = f0_up_val(f0arr, pos);
    acc = first ? node : __fadd_rn(acc, node);
  }
  return acc;
}

// ---------- init: twiddles, window, f0 ----------
__global__ __launch_bounds__(256) void init_tables(const float* __restrict__ logf0,
                                                   float* __restrict__ W) {
  int g = blockIdx.x * 256 + threadIdx.x;
  float* twc = W + 2 * L_TOT;
  float* tws = twc + 512;
  float* wh  = twc + 1024;
  float* f0arr = twc + 2048;
  if (g < 512) {
    double a = (double)g * 3.14159265358979323846 / 512.0; // 2*pi*g/1024
    twc[g] = (float)cos(a);
    tws[g] = (float)sin(a);
  }
  if (g < 1024) {
    double a = (double)g * 3.14159265358979323846 / 512.0;
    wh[g] = (float)(0.5 - 0.5 * cos(a));
  }
  if (g >= 2048 && g < 2048 + NFR) {
    f0arr[g - 2048] = (float)exp((double)logf0[g - 2048]); // correctly-rounded expf
  }
}

// ---------- cumsum tree, levels 1..11; store only >=10 (pulse builds 1..9 in LDS) ----------
__global__ __launch_bounds__(256) void tree_kernel(float* W) {
  const float* f0arr = W + 2 * L_TOT + 2048;
  __shared__ float A[2048];
  __shared__ float B[1024];
  int tid = threadIdx.x;
  int base = blockIdx.x * 2048;
  for (int i = tid; i < 2048; i += 256) A[i] = f0_up_val(f0arr, base + i);
  __syncthreads();
  float* src = A;
  float* dst = B;
  int cnt = 1024;
  for (int a = 1; a <= 11; ++a) {
    int gbase = base >> a;
    for (int i = tid; i < cnt; i += 256) {
      float v = __fadd_rn(src[2 * i], src[2 * i + 1]);
      dst[i] = v;
      if (a >= 10) W[lvl_off(a) + gbase + i] = v;
    }
    __syncthreads();
    float* tmp = src; src = dst; dst = tmp;
    cnt >>= 1;
  }
}

// ---------- cumsum tree, levels 12..22 ----------
__global__ __launch_bounds__(256) void tree_top_kernel(float* W) {
  __shared__ float A[2048];
  __shared__ float B[1024];
  int tid = threadIdx.x;
  for (int i = tid; i < 2048; i += 256) A[i] = W[lvl_off(11) + i];
  __syncthreads();
  float* src = A;
  float* dst = B;
  int cnt = 1024;
  for (int a = 12; a <= 22; ++a) {
    for (int i = tid; i < cnt; i += 256) {
      float v = __fadd_rn(src[2 * i], src[2 * i + 1]);
      dst[i] = v;
      W[lvl_off(a) + i] = v;
    }
    __syncthreads();
    float* tmp = src; src = dst; dst = tmp;
    cnt >>= 1;
  }
}

// ---------- impulse train: 1024 samples/block, 4 per thread ----------
// Levels 1..9 rebuilt in LDS from the block's f0_up values (bit-exact: block base
// is 1024-aligned, so local nodes are the same dyadic pairwise sums). Top fold
// (levels 22..10 of base) is block-uniform. Output written as float4.
__global__ __launch_bounds__(256) void pulse_kernel(float* W) {
  const float* f0arr = W + 2 * L_TOT + 2048;
  __shared__ float f0v[1024];
  __shared__ float Tl[1022];  // level a at offset 1024-(1024>>(a-1)), size 1024>>a
  __shared__ float P[1026];
  int tid = threadIdx.x;
  int base = blockIdx.x * 1024;

  for (int c = 0; c < 4; ++c)
    f0v[tid + 256 * c] = f0_up_val(f0arr, base + tid + 256 * c);
  __syncthreads();
  Tl[tid]       = __fadd_rn(f0v[2 * tid], f0v[2 * tid + 1]);
  Tl[256 + tid] = __fadd_rn(f0v[512 + 2 * tid], f0v[512 + 2 * tid + 1]);
  __syncthreads();
  Tl[512 + tid] = __fadd_rn(Tl[2 * tid], Tl[2 * tid + 1]);
  __syncthreads();
  if (tid < 128) Tl[768 + tid]  = __fadd_rn(Tl[512 + 2 * tid], Tl[512 + 2 * tid + 1]);
  __syncthreads();
  if (tid < 64)  Tl[896 + tid]  = __fadd_rn(Tl[768 + 2 * tid], Tl[768 + 2 * tid + 1]);
  __syncthreads();
  if (tid < 32)  Tl[960 + tid]  = __fadd_rn(Tl[896 + 2 * tid], Tl[896 + 2 * tid + 1]);
  __syncthreads();
  if (tid < 16)  Tl[992 + tid]  = __fadd_rn(Tl[960 + 2 * tid], Tl[960 + 2 * tid + 1]);
  __syncthreads();
  if (tid < 8)   Tl[1008 + tid] = __fadd_rn(Tl[992 + 2 * tid], Tl[992 + 2 * tid + 1]);
  __syncthreads();
  if (tid < 4)   Tl[1016 + tid] = __fadd_rn(Tl[1008 + 2 * tid], Tl[1008 + 2 * tid + 1]);
  __syncthreads();
  if (tid < 2)   Tl[1020 + tid] = __fadd_rn(Tl[1016 + 2 * tid], Tl[1016 + 2 * tid + 1]);
  __syncthreads();

  // block-uniform top fold (levels 22..10 of base)
  float accT = 0.0f;
  bool firstT = true;
  {
    int pos = 0;
    for (int a = 22; a >= 10; --a) {
      if (base & (1 << a)) {
        float node = W[lvl_off(a) + (pos >> a)];
        accT = firstT ? node : __fadd_rn(accT, node);
        firstT = false;
        pos += (1 << a);
      }
    }
  }

  for (int c = 0; c < 4; ++c) {
    int r = 4 * tid + 1 + c;           // r in [1, 1024]
    if (r <= 1023) {
      float acc = accT;
      bool first = firstT;
      int lpos = 0;
      for (int a = 9; a >= 1; --a) {
        if (r & (1 << a)) {
          float node = Tl[1024 - (1024 >> (a - 1)) + (lpos >> a)];
          acc = first ? node : __fadd_rn(acc, node);
          first = false;
          lpos += (1 << a);
        }
      }
      if (r & 1) {
        float node = f0v[lpos];
        acc = first ? node : __fadd_rn(acc, node);
      }
      P[r] = acc;
    } else {
      P[1024] = prefix_sum(W, f0arr, base + 1024);   // carry into top bits
    }
  }
  if (tid == 0) {
    int m2 = base + 1025;
    P[1025] = (m2 <= L_TOT) ? prefix_sum(W, f0arr, m2) : 0.0f;
  }
  __syncthreads();

  float o[4];
  for (int c = 0; c < 4; ++c) {
    int i = base + 4 * tid + c;
    float P1 = P[4 * tid + 1 + c];
    float P2 = (i == L_TOT - 1) ? prefix_sum(W, f0arr, 1)  // roll(-1) wrap
                                : P[4 * tid + 2 + c];
    float t1 = __fdiv_rn(P1, 24000.0f);
    float saw1 = __fadd_rn(t1, -floorf(t1));
    float t2 = __fdiv_rn(P2, 24000.0f);
    float saw2 = __fadd_rn(t2, -floorf(t2));
    float cc = __fdiv_rn(f0v[4 * tid + c], 24000.0f);
    o[c] = __fadd_rn(__fadd_rn(saw1, -saw2), cc);
  }
  *(float4*)&W[L_TOT + base + 4 * tid] = make_float4(o[0], o[1], o[2], o[3]);
}

// ---------- Stockham autosort radix-4 FFT, N=1024, 256 threads, float2 LDS ----------
// Identical arithmetic to R6/R7 (validated); complex values packed as float2 so
// LDS ops are ds_read_b64/ds_write_b64 (half the instruction count).
// Result lands in P2buf after 5 stages (odd number of swaps).
template <int DIR>
__device__ void fft1024_r4(float2* X, float2* P2buf, const float2* tw) {
  int tid = threadIdx.x;
  float2* S = X;
  float2* D = P2buf;
  __syncthreads();
#pragma unroll
  for (int s = 0; s < 5; ++s) {
    int m = 1 << (2 * s);
    int b = tid;
    int t = b & ~(m - 1);
    float2 twu = tw[t];
    float2 twv = tw[2 * t];
    float ur = twu.x, ui = (DIR > 0) ? twu.y : -twu.y;
    float vr = twv.x, vi = (DIR > 0) ? twv.y : -twv.y;
    float w3r = ur * vr - ui * vi;      // w^{3t} = u*v
    float w3i = ur * vi + ui * vr;
    float2 x0 = S[b], x1 = S[b + 256], x2 = S[b + 512], x3 = S[b + 768];
    float s0r = x0.x + x2.x, s0i = x0.y + x2.y;
    float s1r = x1.x + x3.x, s1i = x1.y + x3.y;
    float d0r = x0.x - x2.x, d0i = x0.y - x2.y;
    float e1r = x1.x - x3.x, e1i = x1.y - x3.y;
    float ser = (DIR > 0) ? -e1i : e1i;   // DIR*i*(x1-x3)
    float sei = (DIR > 0) ? e1r : -e1r;
    int d0 = b + 3 * t;                 // 4jm + k
    D[d0] = make_float2(s0r + s1r, s0i + s1i);
    float t1r = d0r + ser, t1i = d0i + sei;
    D[d0 + m] = make_float2(t1r * ur - t1i * ui, t1r * ui + t1i * ur);
    float t2r = s0r - s1r, t2i = s0i - s1i;
    D[d0 + 2 * m] = make_float2(t2r * vr - t2i * vi, t2r * vi + t2i * vr);
    float t3r = d0r - ser, t3i = d0i - sei;
    D[d0 + 3 * m] = make_float2(t3r * w3r - t3i * w3i, t3r * w3i + t3i * w3r);
    __syncthreads();
    float2* tmp = S; S = D; D = tmp;
  }
}

// Hann window from the twiddle table: w(i) = 0.5 - 0.5*cos(2*pi*i/1024)
__device__ __forceinline__ float hann_w(int i, const float2* tw) {
  float c = (i == 512) ? -1.0f : ((i < 512) ? tw[i].x : tw[1024 - i].x);
  return 0.5f - 0.5f * c;
}

// spectral combine for one bin: H[k] <- Sp[k]*H[k] + Sn[k]*An
__device__ __forceinline__ void combine_one(int k, float An, const float2* Y, float2* H) {
  int k2 = (1024 - k) & 1023;
  float2 z = Y[k], mm = Y[k2];
  float Ar = 0.5f * (z.x + mm.x), Ai = 0.5f * (z.y - mm.y);  // even (noise) part
  float Br = 0.5f * (z.y + mm.y), Bi = 0.5f * (mm.x - z.x);  // odd (pulse) part
  float2 h = H[k];
  H[k] = make_float2(Br * h.x - Bi * h.y + Ar * An,
                     Br * h.y + Bi * h.x + Ai * An);
}

// ---------- per-block fused kernel: TWO adjacent frames, 5 FFTs (validated R7) ----------
// OLA contributions pre-scaled by 1/1536 = (1/1024)*(1/1.5): interior wsq == 1.5
// exactly (periodic hann, hop=N/4: the 4 cos phases cancel). Edges fixed by finalize.
__global__ __launch_bounds__(256) void column_kernel(
    const float* __restrict__ noise,
    const float* __restrict__ envn,
    const float* __restrict__ envp,
    const float* __restrict__ W,
    float* __restrict__ out) {
  __shared__ float2 F[1024], Y[1024];    // FFT ping-pong (input in F, result in Y)
  __shared__ float2 hA[513], hB[513];
  __shared__ float2 tw[512];
  int tid = threadIdx.x;
  int bid = blockIdx.x;
  // XCD swizzle: each XCD streams a contiguous frame range (env L2 locality).
  int g = (bid & 7) * 1024 + (bid >> 3);
  int fA = 2 * g;                        // frames fA, fA+1
  const float* pulse = W + L_TOT;
  const float* gtab = W + 2 * L_TOT;

  for (int i = tid; i < 512; i += 256) tw[i] = make_float2(gtab[i], gtab[512 + i]);
  for (int k = tid; k < 513; k += 256) {
    float2 e = *(const float2*)&envp[k * NFR + fA];   // fA even -> 8B aligned
    hA[k] = e;                                        // (log ampA, log ampB)
  }
  __syncthreads();

  // ---- (1) packed cepstrum: z = envA_sym + i*envB_sym (both real even) ----
  for (int i = tid; i < 1024; i += 256) {
    int k = (i <= 512) ? i : 1024 - i;
    F[i] = hA[k];
  }
  fft1024_r4<+1>(F, Y, tw);
  // cep fold: scales 2^-10 / 2^-9 are exact; identical rounding to R5-R7
  {
    float2 a0 = Y[tid], a1 = Y[tid + 256], a2 = Y[tid + 512];
    float s0 = (tid == 0) ? (1.0f / 1024.0f) : (2.0f / 1024.0f);
    F[tid] = make_float2(a0.x * s0, a0.y * s0);
    F[tid + 256] = make_float2(a1.x * (2.0f / 1024.0f), a1.y * (2.0f / 1024.0f));
    F[tid + 512] = (tid == 0) ? make_float2(a2.x * (1.0f / 1024.0f),
                                            a2.y * (1.0f / 1024.0f))
                              : make_float2(0.0f, 0.0f);
    F[tid + 768] = make_float2(0.0f, 0.0f);
  }
  // ---- (2) packed rfft of two real cepstra; hermitian unpack; H=exp ----
  fft1024_r4<-1>(F, Y, tw);
  for (int k = tid; k < 513; k += 256) {
    int k2 = (1024 - k) & 1023;
    float2 z = Y[k], mm = Y[k2];
    float GAr = 0.5f * (z.x + mm.x), GAi = 0.5f * (z.y - mm.y);
    float GBr = 0.5f * (z.y + mm.y), GBi = 0.5f * (mm.x - z.x);
    float er = expf(GAr);
    float si, co;
    sincosf(GAi, &si, &co);
    hA[k] = make_float2(er * co, er * si);
    er = expf(GBr);
    sincosf(GBi, &si, &co);
    hB[k] = make_float2(er * co, er * si);
  }

  // ---- (3) frame A: pack z = noise + i*pulse (windowed, reflect-padded) ----
  for (int i = tid; i < 1024; i += 256) {
    int q = 256 * fA - 256 + i;
    if (q < 0) q = -q;
    else if (q >= L_TOT) q = 2 * L_TOT - 2 - q;
    float wv = hann_w(i, tw);
    F[i] = make_float2(noise[q] * wv, pulse[q] * wv);
  }
  fft1024_r4<-1>(F, Y, tw);
  float2 eA0 = *(const float2*)&envn[tid * NFR + fA];
  combine_one(tid, expf(eA0.x), Y, hA);
  float2 eA1 = *(const float2*)&envn[(tid + 256) * NFR + fA];
  combine_one(tid + 256, expf(eA1.x), Y, hA);
  float2 eA2 = make_float2(0.0f, 0.0f);
  if (tid == 0) {
    eA2 = *(const float2*)&envn[512 * NFR + fA];
    combine_one(512, expf(eA2.x), Y, hA);
  }

  // ---- (4) frame B ----
  for (int i = tid; i < 1024; i += 256) {
    int q = 256 * fA + i;                     // frame fA+1 start - 256 (q >= 0)
    if (q >= L_TOT) q = 2 * L_TOT - 2 - q;
    float wv = hann_w(i, tw);
    F[i] = make_float2(noise[q] * wv, pulse[q] * wv);
  }
  fft1024_r4<-1>(F, Y, tw);
  combine_one(tid, expf(eA0.y), Y, hB);
  combine_one(tid + 256, expf(eA1.y), Y, hB);
  if (tid == 0) combine_one(512, expf(eA2.y), Y, hB);
  __syncthreads();   // hA/hB must be visible cross-thread below

  // ---- (5) packed hermitian inverse: Z = YA_full + i*YB_full ----
  for (int i = tid; i < 1024; i += 256) {
    if (i <= 512) {
      F[i] = make_float2(hA[i].x - hB[i].y, hA[i].y + hB[i].x);
    } else {
      int j = 1024 - i;
      F[i] = make_float2(hA[j].x + hB[j].y, hB[j].x - hA[j].y);
    }
  }
  fft1024_r4<+1>(F, Y, tw);
  for (int i = tid; i < 1024; i += 256) {
    float wv = hann_w(i, tw) * (1.0f / 1536.0f);   // 1/1024 FFT scale * 1/1.5 wsq
    float ya = Y[i].x * wv;
    float yb = Y[i].y * wv;
    int tA = 256 * fA + i - 512;
    if (tA >= 0 && tA < OUTN) atomicAdd(&out[tA], ya);
    int tB = tA + 256;
    if (tB >= 0 && tB < OUTN) atomicAdd(&out[tB], yb);
  }
}

// ---------- edge fix-up: first/last 256 samples have <4 window terms ----------
// Interior already exact (wsq==1.5 handled in column). out *= 1.5/max(wsq,eps).
__global__ __launch_bounds__(256) void finalize_kernel(float* __restrict__ out,
                                                       const float* __restrict__ W) {
  const float* wh = W + 2 * L_TOT + 1024;
  int tid = threadIdx.x;
  int t = (blockIdx.x == 0) ? tid : (OUTN - 256 + tid);
  int p = t + 512;
  int jmin = max(0, (p - 768) >> 8);
  int jmax = min(NFR - 1, p >> 8);
  float wsq = 0.0f;
  for (int j = jmin; j <= jmax; ++j) {
    float w = wh[p - 256 * j];
    wsq += w * w;
  }
  out[t] = out[t] * (1.5f / fmaxf(wsq, 1e-11f));
}

extern "C" void kernel_launch(void* const* d_in, const int* in_sizes, int n_in,
                              void* d_out, int out_size, void* d_ws, size_t ws_size,
                              hipStream_t stream) {
  const float* logf0 = (const float*)d_in[0];
  const float* envn  = (const float*)d_in[1];
  const float* envp  = (const float*)d_in[2];
  const float* noise = (const float*)d_in[3];
  float* out = (float*)d_out;
  float* W = (float*)d_ws;

  init_tables<<<dim3(72), dim3(256), 0, stream>>>(logf0, W);
  tree_kernel<<<dim3(2048), dim3(256), 0, stream>>>(W);
  tree_top_kernel<<<dim3(1), dim3(256), 0, stream>>>(W);
  pulse_kernel<<<dim3(L_TOT / 1024), dim3(256), 0, stream>>>(W);
  hipMemsetAsync(d_out, 0, (size_t)out_size * sizeof(float), stream);
  column_kernel<<<dim3(NFR / 2), dim3(256), 0, stream>>>(noise, envn, envp, W, out);
  finalize_kernel<<<dim3(2), dim3(256), 0, stream>>>(out, W);
}

// Round 9
// 255.955 us; speedup vs baseline: 3.1559x; 1.0366x over previous
//
#include <hip/hip_runtime.h>
#include <math.h>

#define L_TOT 4194304   // 2^22 upsampled samples
#define NFR   16384     // frames / f0 length
#define OUTN  4194048   // output length

// ---------- workspace layout (floats) ----------
// [0, L_TOT)                : cumsum tree levels 11..22 (packed; lower levels in LDS)
// [L_TOT, 2*L_TOT)          : pulse signal
// [2*L_TOT + 0,   +512)     : twiddle cos  (cos(2*pi*j/1024))
// [2*L_TOT + 512, +1024)    : twiddle sin
// [2*L_TOT + 1024,+2048)    : hann window (1024) — used by edge finalize
// [2*L_TOT + 2048,+2048+NFR): f0 = exp(log_f0)

__device__ __forceinline__ int lvl_off(int a) {
  return L_TOT - (L_TOT >> (a - 1));
}

// linear_interp(exp(log_f0), 256) at position j — matches reference rounding (no FMA)
__device__ __forceinline__ float f0_up_val(const float* f0arr, int j) {
  float pos = __fadd_rn(__fmul_rn(__fadd_rn((float)j, 0.5f), 1.0f / 256.0f), -0.5f);
  pos = fminf(fmaxf(pos, 0.0f), 16383.0f);
  int lo = (int)pos;
  int hi = min(lo + 1, NFR - 1);
  float frac = __fadd_rn(pos, -(float)lo);
  float a = __fmul_rn(f0arr[lo], __fadd_rn(1.0f, -frac));
  float b = __fmul_rn(f0arr[hi], frac);
  return __fadd_rn(a, b);
}

// full prefix sum replicating jax.lax.associative_scan bit-exactly (validated R4-R8).
// Only called with m ≡ 0 or ±1 (mod 4096), or m=1 -> never reads levels 1..10.
__device__ float prefix_sum(const float* W, const float* f0arr, int m) {
  float acc = 0.0f;
  bool first = true;
  int pos = 0;
  for (int a = 22; a >= 1; --a) {
    if (m & (1 << a)) {
      float node = W[lvl_off(a) + (pos >> a)];
      acc = first ? node : __fadd_rn(acc, node);
      first = false;
      pos += (1 << a);
    }
  }
  if (m & 1) {
    float node = f0_up_val(f0arr, pos);
    acc = first ? node : __fadd_rn(acc, node);
  }
  return acc;
}

// ---------- init: twiddles, window, f0 ----------
__global__ __launch_bounds__(256) void init_tables(const float* __restrict__ logf0,
                                                   float* __restrict__ W) {
  int g = blockIdx.x * 256 + threadIdx.x;
  float* twc = W + 2 * L_TOT;
  float* tws = twc + 512;
  float* wh  = twc + 1024;
  float* f0arr = twc + 2048;
  if (g < 512) {
    double a = (double)g * 3.14159265358979323846 / 512.0; // 2*pi*g/1024
    twc[g] = (float)cos(a);
    tws[g] = (float)sin(a);
  }
  if (g < 1024) {
    double a = (double)g * 3.14159265358979323846 / 512.0;
    wh[g] = (float)(0.5 - 0.5 * cos(a));
  }
  if (g >= 2048 && g < 2048 + NFR) {
    f0arr[g - 2048] = (float)exp((double)logf0[g - 2048]); // correctly-rounded expf
  }
}

// ---------- cumsum tree: build levels 1..11, store only level 11 ----------
__global__ __launch_bounds__(256) void tree_kernel(float* W) {
  const float* f0arr = W + 2 * L_TOT + 2048;
  __shared__ float A[2048];
  __shared__ float B[1024];
  int tid = threadIdx.x;
  int base = blockIdx.x * 2048;
  for (int i = tid; i < 2048; i += 256) A[i] = f0_up_val(f0arr, base + i);
  __syncthreads();
  float* src = A;
  float* dst = B;
  int cnt = 1024;
  for (int a = 1; a <= 11; ++a) {
    int gbase = base >> a;
    for (int i = tid; i < cnt; i += 256) {
      float v = __fadd_rn(src[2 * i], src[2 * i + 1]);
      dst[i] = v;
      if (a == 11) W[lvl_off(11) + gbase + i] = v;
    }
    __syncthreads();
    float* tmp = src; src = dst; dst = tmp;
    cnt >>= 1;
  }
}

// ---------- cumsum tree, levels 12..22 ----------
__global__ __launch_bounds__(256) void tree_top_kernel(float* W) {
  __shared__ float A[2048];
  __shared__ float B[1024];
  int tid = threadIdx.x;
  for (int i = tid; i < 2048; i += 256) A[i] = W[lvl_off(11) + i];
  __syncthreads();
  float* src = A;
  float* dst = B;
  int cnt = 1024;
  for (int a = 12; a <= 22; ++a) {
    for (int i = tid; i < cnt; i += 256) {
      float v = __fadd_rn(src[2 * i], src[2 * i + 1]);
      dst[i] = v;
      W[lvl_off(a) + i] = v;
    }
    __syncthreads();
    float* tmp = src; src = dst; dst = tmp;
    cnt >>= 1;
  }
}

// ---------- impulse train v3: 4096 samples/block, 16 per thread ----------
// Three-tier exact fold: low bits (3..0) from per-thread REGISTER pairwise sums,
// mid bits (11..4) from a per-thread LDS-tree walk, top bits (22..12) block-
// uniform. Identical association to prefix_sum -> bit-exact (validated R4-R8).
__global__ __launch_bounds__(256) void pulse_kernel(float* W) {
  const float* f0arr = W + 2 * L_TOT + 2048;
  __shared__ float Tl[510];   // levels 4..11: off(a) = 512 - (512 >> (a-4))
  __shared__ float P[4100];   // P[r] = prefix(base+r), r in [1,4097]
  int tid = threadIdx.x;
  int base = blockIdx.x * 4096;

  float v[16];
#pragma unroll
  for (int c = 0; c < 16; ++c) v[c] = f0_up_val(f0arr, base + 16 * tid + c);
  float s2[8], s4[4], s8[2];
#pragma unroll
  for (int j = 0; j < 8; ++j) s2[j] = __fadd_rn(v[2 * j], v[2 * j + 1]);
#pragma unroll
  for (int j = 0; j < 4; ++j) s4[j] = __fadd_rn(s2[2 * j], s2[2 * j + 1]);
  s8[0] = __fadd_rn(s4[0], s4[1]);
  s8[1] = __fadd_rn(s4[2], s4[3]);
  Tl[tid] = __fadd_rn(s8[0], s8[1]);          // level-4 leaf (s16)
  __syncthreads();
  if (tid < 128) Tl[256 + tid] = __fadd_rn(Tl[2 * tid], Tl[2 * tid + 1]);
  __syncthreads();
  if (tid < 64)  Tl[384 + tid] = __fadd_rn(Tl[256 + 2 * tid], Tl[256 + 2 * tid + 1]);
  __syncthreads();
  if (tid < 32)  Tl[448 + tid] = __fadd_rn(Tl[384 + 2 * tid], Tl[384 + 2 * tid + 1]);
  __syncthreads();
  if (tid < 16)  Tl[480 + tid] = __fadd_rn(Tl[448 + 2 * tid], Tl[448 + 2 * tid + 1]);
  __syncthreads();
  if (tid < 8)   Tl[496 + tid] = __fadd_rn(Tl[480 + 2 * tid], Tl[480 + 2 * tid + 1]);
  __syncthreads();
  if (tid < 4)   Tl[504 + tid] = __fadd_rn(Tl[496 + 2 * tid], Tl[496 + 2 * tid + 1]);
  __syncthreads();
  if (tid < 2)   Tl[508 + tid] = __fadd_rn(Tl[504 + 2 * tid], Tl[504 + 2 * tid + 1]);
  __syncthreads();

  // top fold (levels 22..12 of base) — block-uniform broadcast loads
  float accT = 0.0f;
  bool firstT = true;
  {
    int pos = 0;
    for (int a = 22; a >= 12; --a) {
      if (base & (1 << a)) {
        float node = W[lvl_off(a) + (pos >> a)];
        accT = firstT ? node : __fadd_rn(accT, node);
        firstT = false;
        pos += (1 << a);
      }
    }
  }
  // mid fold (levels 11..4 of r_hi = 16*tid) — once per thread
  float accM = accT;
  bool firstM = firstT;
  {
    int rh = 16 * tid;
    int lpos = 0;
    for (int a = 11; a >= 4; --a) {
      if (rh & (1 << a)) {
        float node = Tl[512 - (512 >> (a - 4)) + (lpos >> a)];
        accM = firstM ? node : __fadd_rn(accM, node);
        firstM = false;
        lpos += (1 << a);
      }
    }
  }
  if (tid >= 1) P[16 * tid] = accM;          // prefix(base+16t): no low bits
  // low fold (bits 3..0 of c) — register sums only
#pragma unroll
  for (int c = 1; c <= 15; ++c) {
    float acc = accM;
    bool first = firstM;
    int lp = 0;
    if (c & 8) { float n = s8[lp >> 3]; acc = first ? n : __fadd_rn(acc, n); first = false; lp += 8; }
    if (c & 4) { float n = s4[lp >> 2]; acc = first ? n : __fadd_rn(acc, n); first = false; lp += 4; }
    if (c & 2) { float n = s2[lp >> 1]; acc = first ? n : __fadd_rn(acc, n); first = false; lp += 2; }
    if (c & 1) { float n = v[lp];       acc = first ? n : __fadd_rn(acc, n); }
    P[16 * tid + c] = acc;
  }
  if (tid == 0) P[4096] = prefix_sum(W, f0arr, base + 4096);
  if (tid == 1) {
    int m2 = base + 4097;
    P[4097] = (m2 <= L_TOT) ? prefix_sum(W, f0arr, m2) : 0.0f;
  }
  __syncthreads();

  float o[16];
#pragma unroll
  for (int c = 0; c < 16; ++c) {
    int i = base + 16 * tid + c;
    float P1 = P[16 * tid + c + 1];
    float P2 = (i == L_TOT - 1) ? prefix_sum(W, f0arr, 1)  // roll(-1) wrap
                                : P[16 * tid + c + 2];
    float t1 = __fdiv_rn(P1, 24000.0f);
    float saw1 = __fadd_rn(t1, -floorf(t1));
    float t2 = __fdiv_rn(P2, 24000.0f);
    float saw2 = __fadd_rn(t2, -floorf(t2));
    float cc = __fdiv_rn(v[c], 24000.0f);
    o[c] = __fadd_rn(__fadd_rn(saw1, -saw2), cc);
  }
#pragma unroll
  for (int k = 0; k < 4; ++k)
    *(float4*)&W[L_TOT + base + 16 * tid + 4 * k] =
        make_float4(o[4 * k], o[4 * k + 1], o[4 * k + 2], o[4 * k + 3]);
}

// ---------- Stockham radix-4 FFT, N=1024, 256 threads, quarter twiddle table ----------
// tw[0..256] holds w^t = (cos,sin)(2*pi*t/1024) for t<=256; t = tid&~(m-1) <= 255.
// v = w^{2t} = u^2, w^{3t} = u*v derived in registers (~1e-7 rounding, within tol).
// Result lands in Pb after 5 stages.
template <int DIR>
__device__ void fft1024_r4(float2* X, float2* Pb, const float2* tw) {
  int tid = threadIdx.x;
  float2* S = X;
  float2* D = Pb;
  __syncthreads();
#pragma unroll
  for (int s = 0; s < 5; ++s) {
    int m = 1 << (2 * s);
    int b = tid;
    int t = b & ~(m - 1);
    float2 twu = tw[t];
    float ur = twu.x, ui = (DIR > 0) ? twu.y : -twu.y;
    float vr = ur * ur - ui * ui;       // w^{2t} = u^2
    float vi = 2.0f * ur * ui;
    float w3r = ur * vr - ui * vi;      // w^{3t} = u*v
    float w3i = ur * vi + ui * vr;
    float2 x0 = S[b], x1 = S[b + 256], x2 = S[b + 512], x3 = S[b + 768];
    float s0r = x0.x + x2.x, s0i = x0.y + x2.y;
    float s1r = x1.x + x3.x, s1i = x1.y + x3.y;
    float d0r = x0.x - x2.x, d0i = x0.y - x2.y;
    float e1r = x1.x - x3.x, e1i = x1.y - x3.y;
    float ser = (DIR > 0) ? -e1i : e1i;   // DIR*i*(x1-x3)
    float sei = (DIR > 0) ? e1r : -e1r;
    int d0 = b + 3 * t;                 // 4jm + k
    D[d0] = make_float2(s0r + s1r, s0i + s1i);
    float t1r = d0r + ser, t1i = d0i + sei;
    D[d0 + m] = make_float2(t1r * ur - t1i * ui, t1r * ui + t1i * ur);
    float t2r = s0r - s1r, t2i = s0i - s1i;
    D[d0 + 2 * m] = make_float2(t2r * vr - t2i * vi, t2r * vi + t2i * vr);
    float t3r = d0r - ser, t3i = d0i - sei;
    D[d0 + 3 * m] = make_float2(t3r * w3r - t3i * w3i, t3r * w3i + t3i * w3r);
    __syncthreads();
    float2* tmp = S; S = D; D = tmp;
  }
}

// Hann from quarter table: w(i) = 0.5 - 0.5*cos(2*pi*i/1024)
// mirror: i>512 -> 1024-i; j in (256,512] -> cos = -tw[512-j].x; tw[256].x == 0.
__device__ __forceinline__ float hann_w(int i, const float2* tw) {
  int j = (i > 512) ? (1024 - i) : i;
  float c = (j <= 256) ? tw[j].x : -tw[512 - j].x;
  return 0.5f - 0.5f * c;
}

// spectral combine for one bin: H[k] <- Sp[k]*H[k] + Sn[k]*An
__device__ __forceinline__ void combine_one(int k, float An, const float2* Y, float2* H) {
  int k2 = (1024 - k) & 1023;
  float2 z = Y[k], mm = Y[k2];
  float Ar = 0.5f * (z.x + mm.x), Ai = 0.5f * (z.y - mm.y);  // even (noise) part
  float Br = 0.5f * (z.y + mm.y), Bi = 0.5f * (mm.x - z.x);  // odd (pulse) part
  float2 h = H[k];
  H[k] = make_float2(Br * h.x - Bi * h.y + Ar * An,
                     Br * h.y + Bi * h.x + Ai * An);
}

// ---------- per-block fused kernel: TWO adjacent frames, 5 FFTs (validated R7/R8) ----------
// LDS 26648 B -> 6 blocks/CU (was 5). OLA pre-scaled by 1/1536 (interior wsq==1.5).
__global__ __launch_bounds__(256) void column_kernel(
    const float* __restrict__ noise,
    const float* __restrict__ envn,
    const float* __restrict__ envp,
    const float* __restrict__ W,
    float* __restrict__ out) {
  __shared__ float2 F[1024], Y[1024];    // FFT ping-pong (input in F, result in Y)
  __shared__ float2 hA[513], hB[513];
  __shared__ float2 tw[257];
  int tid = threadIdx.x;
  int bid = blockIdx.x;
  // XCD swizzle: each XCD streams a contiguous frame range (env L2 locality).
  int g = (bid & 7) * 1024 + (bid >> 3);
  int fA = 2 * g;                        // frames fA, fA+1
  const float* pulse = W + L_TOT;
  const float* gtab = W + 2 * L_TOT;

  for (int i = tid; i < 257; i += 256) tw[i] = make_float2(gtab[i], gtab[512 + i]);
  for (int k = tid; k < 513; k += 256) {
    float2 e = *(const float2*)&envp[k * NFR + fA];   // fA even -> 8B aligned
    hA[k] = e;                                        // (log ampA, log ampB)
  }
  __syncthreads();

  // ---- (1) packed cepstrum: z = envA_sym + i*envB_sym (both real even) ----
  for (int i = tid; i < 1024; i += 256) {
    int k = (i <= 512) ? i : 1024 - i;
    F[i] = hA[k];
  }
  fft1024_r4<+1>(F, Y, tw);
  // cep fold: scales 2^-10 / 2^-9 are exact; identical rounding to R5-R8
  {
    float2 a0 = Y[tid], a1 = Y[tid + 256], a2 = Y[tid + 512];
    float s0 = (tid == 0) ? (1.0f / 1024.0f) : (2.0f / 1024.0f);
    F[tid] = make_float2(a0.x * s0, a0.y * s0);
    F[tid + 256] = make_float2(a1.x * (2.0f / 1024.0f), a1.y * (2.0f / 1024.0f));
    F[tid + 512] = (tid == 0) ? make_float2(a2.x * (1.0f / 1024.0f),
                                            a2.y * (1.0f / 1024.0f))
                              : make_float2(0.0f, 0.0f);
    F[tid + 768] = make_float2(0.0f, 0.0f);
  }
  // ---- (2) packed rfft of two real cepstra; hermitian unpack; H=exp ----
  fft1024_r4<-1>(F, Y, tw);
  for (int k = tid; k < 513; k += 256) {
    int k2 = (1024 - k) & 1023;
    float2 z = Y[k], mm = Y[k2];
    float GAr = 0.5f * (z.x + mm.x), GAi = 0.5f * (z.y - mm.y);
    float GBr = 0.5f * (z.y + mm.y), GBi = 0.5f * (mm.x - z.x);
    float er = expf(GAr);
    float si, co;
    sincosf(GAi, &si, &co);
    hA[k] = make_float2(er * co, er * si);
    er = expf(GBr);
    sincosf(GBi, &si, &co);
    hB[k] = make_float2(er * co, er * si);
  }

  // ---- (3) frame A: pack z = noise + i*pulse (windowed, reflect-padded) ----
  for (int i = tid; i < 1024; i += 256) {
    int q = 256 * fA - 256 + i;
    if (q < 0) q = -q;
    else if (q >= L_TOT) q = 2 * L_TOT - 2 - q;
    float wv = hann_w(i, tw);
    F[i] = make_float2(noise[q] * wv, pulse[q] * wv);
  }
  fft1024_r4<-1>(F, Y, tw);
  float2 eA0 = *(const float2*)&envn[tid * NFR + fA];
  combine_one(tid, expf(eA0.x), Y, hA);
  float2 eA1 = *(const float2*)&envn[(tid + 256) * NFR + fA];
  combine_one(tid + 256, expf(eA1.x), Y, hA);
  float2 eA2 = make_float2(0.0f, 0.0f);
  if (tid == 0) {
    eA2 = *(const float2*)&envn[512 * NFR + fA];
    combine_one(512, expf(eA2.x), Y, hA);
  }

  // ---- (4) frame B ----
  for (int i = tid; i < 1024; i += 256) {
    int q = 256 * fA + i;                     // frame fA+1 start - 256 (q >= 0)
    if (q >= L_TOT) q = 2 * L_TOT - 2 - q;
    float wv = hann_w(i, tw);
    F[i] = make_float2(noise[q] * wv, pulse[q] * wv);
  }
  fft1024_r4<-1>(F, Y, tw);
  combine_one(tid, expf(eA0.y), Y, hB);
  combine_one(tid + 256, expf(eA1.y), Y, hB);
  if (tid == 0) combine_one(512, expf(eA2.y), Y, hB);
  __syncthreads();   // hA/hB must be visible cross-thread below

  // ---- (5) packed hermitian inverse: Z = YA_full + i*YB_full ----
  for (int i = tid; i < 1024; i += 256) {
    if (i <= 512) {
      F[i] = make_float2(hA[i].x - hB[i].y, hA[i].y + hB[i].x);
    } else {
      int j = 1024 - i;
      F[i] = make_float2(hA[j].x + hB[j].y, hB[j].x - hA[j].y);
    }
  }
  fft1024_r4<+1>(F, Y, tw);
  for (int i = tid; i < 1024; i += 256) {
    float wv = hann_w(i, tw) * (1.0f / 1536.0f);   // 1/1024 FFT scale * 1/1.5 wsq
    float ya = Y[i].x * wv;
    float yb = Y[i].y * wv;
    int tA = 256 * fA + i - 512;
    if (tA >= 0 && tA < OUTN) atomicAdd(&out[tA], ya);
    int tB = tA + 256;
    if (tB >= 0 && tB < OUTN) atomicAdd(&out[tB], yb);
  }
}

// ---------- edge fix-up: first/last 256 samples have <4 window terms ----------
__global__ __launch_bounds__(256) void finalize_kernel(float* __restrict__ out,
                                                       const float* __restrict__ W) {
  const float* wh = W + 2 * L_TOT + 1024;
  int tid = threadIdx.x;
  int t = (blockIdx.x == 0) ? tid : (OUTN - 256 + tid);
  int p = t + 512;
  int jmin = max(0, (p - 768) >> 8);
  int jmax = min(NFR - 1, p >> 8);
  float wsq = 0.0f;
  for (int j = jmin; j <= jmax; ++j) {
    float w = wh[p - 256 * j];
    wsq += w * w;
  }
  out[t] = out[t] * (1.5f / fmaxf(wsq, 1e-11f));
}

extern "C" void kernel_launch(void* const* d_in, const int* in_sizes, int n_in,
                              void* d_out, int out_size, void* d_ws, size_t ws_size,
                              hipStream_t stream) {
  const float* logf0 = (const float*)d_in[0];
  const float* envn  = (const float*)d_in[1];
  const float* envp  = (const float*)d_in[2];
  const float* noise = (const float*)d_in[3];
  float* out = (float*)d_out;
  float* W = (float*)d_ws;

  init_tables<<<dim3(72), dim3(256), 0, stream>>>(logf0, W);
  tree_kernel<<<dim3(2048), dim3(256), 0, stream>>>(W);
  tree_top_kernel<<<dim3(1), dim3(256), 0, stream>>>(W);
  pulse_kernel<<<dim3(L_TOT / 4096), dim3(256), 0, stream>>>(W);
  hipMemsetAsync(d_out, 0, (size_t)out_size * sizeof(float), stream);
  column_kernel<<<dim3(NFR / 2), dim3(256), 0, stream>>>(noise, envn, envp, W, out);
  finalize_kernel<<<dim3(2), dim3(256), 0, stream>>>(out, W);
}